// Round 4
// baseline (755.529 us; speedup 1.0000x reference)
//
#include <hip/hip_runtime.h>
#include <math.h>

// Problem dims
#define N_ 4
#define C_ 512
#define L_ 4096
#define D_ 256
#define K_ 8192
#define NL_ 16384           // N_*L_

// d_out layout (float32 flat): y | code_index(as float) | cb_loss | cm_loss
#define OUT_IDX_OFF (N_*C_*L_)          // 8388608
#define OUT_CB_OFF  (OUT_IDX_OFF + NL_) // 8404992

// ws layout (float units).
#define WS_ZT   0                                  // Zt[16384][256] f32
#define WS_P    (WS_ZT + (size_t)NL_*D_)           // P[8192][512] f32
#define WS_Z2   (WS_P + (size_t)K_*C_)             // Z2[16384][512] bf16 (hi|lo row-major)
#define WS_CB2  (WS_Z2 + (size_t)NL_*D_)           // CB2F[512 c16][16 frag][64 lane][8] bf16
#define WS_PART (WS_CB2 + (size_t)K_*D_)           // Part[16384][4 ks][4] f32 top2 partials
#define WS_WIN  (WS_PART + (size_t)NL_*64*4)       // W_in[256][512]
#define WS_WOUT (WS_WIN + (size_t)D_*C_)           // W_out[512][256]
#define WS_INVN (WS_WOUT + (size_t)C_*D_)          // inv codebook norms [8192]
#define WS_IDX  (WS_INVN + (size_t)K_)             // idx[16384] (int)
#define WS_LOSS (WS_IDX + (size_t)NL_)             // loss accum [4]

typedef __bf16 bf16x8 __attribute__((ext_vector_type(8)));
typedef float  f32x4  __attribute__((ext_vector_type(4)));
typedef unsigned int u32;

__device__ __forceinline__ unsigned short f2bf(float f) {   // round-nearest-even
    u32 u = __float_as_uint(f);
    u32 r = (u + 0x7fffu + ((u >> 16) & 1u)) >> 16;
    return (unsigned short)r;
}
__device__ __forceinline__ float bf2f(unsigned short h) {
    return __uint_as_float(((u32)h) << 16);
}

__device__ __forceinline__ float waveReduceSum64(float s) {
    #pragma unroll
    for (int off = 32; off; off >>= 1) s += __shfl_xor(s, off, 64);
    return s;
}

// prefer (av,ai) over (bv,bi)?  larger value wins; tie -> smaller index
__device__ __forceinline__ bool pref(float av, int ai, float bv, int bi) {
    return (av > bv) || (av == bv && ai < bi);
}
// push candidate (wv,wi) into sorted top2 (v1,i1,v2,i2)
__device__ __forceinline__ void push2(float& v1, int& i1, float& v2, int& i2,
                                      float wv, int wi) {
    if (pref(wv, wi, v1, i1)) { v2 = v1; i2 = i1; v1 = wv; i1 = wi; }
    else if (pref(wv, wi, v2, i2)) { v2 = wv; i2 = wi; }
}

// async global->LDS copy, 16B per lane; lds dest must be wave-uniform base
__device__ __forceinline__ void gload_lds16(const void* g, void* l) {
    __builtin_amdgcn_global_load_lds(
        (const __attribute__((address_space(1))) void*)g,
        (__attribute__((address_space(3))) void*)l,
        16, 0, 0);
}

// ---------------------------------------------------------------------------
// prep: W_in = g*v/||v||, W_out likewise, zero loss accum.
// ---------------------------------------------------------------------------
__global__ __launch_bounds__(64) void prep_kernel(
    const float* __restrict__ in_v, const float* __restrict__ in_g,
    const float* __restrict__ out_v, const float* __restrict__ out_g,
    float* __restrict__ Win, float* __restrict__ Wout,
    float* __restrict__ lossacc)
{
    const int b = blockIdx.x;
    const int t = threadIdx.x;
    if (b == 0 && t < N_) lossacc[t] = 0.0f;
    if (b < D_) {
        const float* v = in_v + (size_t)b * C_;
        float4 a0 = *(const float4*)(v + t * 4);
        float4 a1 = *(const float4*)(v + 256 + t * 4);
        float s = a0.x*a0.x + a0.y*a0.y + a0.z*a0.z + a0.w*a0.w
                + a1.x*a1.x + a1.y*a1.y + a1.z*a1.z + a1.w*a1.w;
        s = waveReduceSum64(s);
        float scale = in_g[b] / sqrtf(s);
        float* w = Win + (size_t)b * C_;
        float4 o0, o1;
        o0.x=a0.x*scale; o0.y=a0.y*scale; o0.z=a0.z*scale; o0.w=a0.w*scale;
        o1.x=a1.x*scale; o1.y=a1.y*scale; o1.z=a1.z*scale; o1.w=a1.w*scale;
        *(float4*)(w + t*4) = o0;
        *(float4*)(w + 256 + t*4) = o1;
    } else {
        const int r = b - D_;
        const float* v = out_v + (size_t)r * D_;
        float4 a0 = *(const float4*)(v + t * 4);
        float s = a0.x*a0.x + a0.y*a0.y + a0.z*a0.z + a0.w*a0.w;
        s = waveReduceSum64(s);
        float scale = out_g[r] / sqrtf(s);
        float4 o0;
        o0.x=a0.x*scale; o0.y=a0.y*scale; o0.z=a0.z*scale; o0.w=a0.w*scale;
        *(float4*)(Wout + (size_t)r * D_ + t*4) = o0;
    }
}

// ---------------------------------------------------------------------------
// cb2: invn[k] = 1/max(||cb_k||,eps).  grid 8192 x 64
// ---------------------------------------------------------------------------
__global__ __launch_bounds__(64) void cb2_kernel(
    const float* __restrict__ cb, float* __restrict__ invn)
{
    const int k = blockIdx.x;
    const int t = threadIdx.x;
    float4 v = *(const float4*)(cb + (size_t)k * D_ + t * 4);
    float s = v.x*v.x + v.y*v.y + v.z*v.z + v.w*v.w;
    s = waveReduceSum64(s);
    if (t == 0) invn[k] = 1.0f / fmaxf(sqrtf(s), 1e-8f);
}

// ---------------------------------------------------------------------------
// cb2f: build B-fragment-ordered split codebook.
// Layout: frag(c16, kc) = 1 KB at ((c16*16 + kc)*64 lanes)*8 shorts.
// MFMA B-operand lane map (16x16x32): lane = (klocal>>3)*16 + n, j = klocal&7.
// kc 0..7: hi(d = kc*32 + klocal), scaled by invn; kc 8..15: lo of same d.
// grid 512 x 256.  thread t: kc = t>>4, n = t&15, covers d-range (kc&7)*32..+31.
// ---------------------------------------------------------------------------
__global__ __launch_bounds__(256) void cb2f_kernel(
    const float* __restrict__ cb, const float* __restrict__ invn,
    unsigned short* __restrict__ CB2F)
{
    const int c16 = blockIdx.x;
    const int t = threadIdx.x;
    const int kc = t >> 4, nl = t & 15;
    const int code = c16 * 16 + nl;
    const float inv = invn[code];
    const float* src = cb + (size_t)code * D_ + (kc & 7) * 32;
    unsigned short* dst = CB2F + ((size_t)(c16 * 16 + kc) * 64) * 8;
    #pragma unroll
    for (int lh = 0; lh < 4; ++lh) {
        float4 x0 = *(const float4*)(src + lh * 8);
        float4 x1 = *(const float4*)(src + lh * 8 + 4);
        float f[8] = {x0.x, x0.y, x0.z, x0.w, x1.x, x1.y, x1.z, x1.w};
        unsigned short o[8];
        #pragma unroll
        for (int j = 0; j < 8; ++j) {
            float v = f[j] * inv;
            unsigned short h = f2bf(v);
            o[j] = (kc < 8) ? h : f2bf(v - bf2f(h));
        }
        unsigned short* dp = dst + (lh * 16 + nl) * 8;
        *(ushort4*)&dp[0] = make_ushort4(o[0], o[1], o[2], o[3]);
        *(ushort4*)&dp[4] = make_ushort4(o[4], o[5], o[6], o[7]);
    }
}

// ---------------------------------------------------------------------------
// z_e GEMM: Zt[n*L+l][d] = sum_c x[n][c][l]*Win[d][c] + in_b[d]; also writes
// bf16 split Z2[row] = [hi | lo] row-major.
// ---------------------------------------------------------------------------
__global__ __launch_bounds__(256) void ze_kernel(
    const float* __restrict__ x, const float* __restrict__ Win,
    const float* __restrict__ inb, float* __restrict__ Zt,
    unsigned short* __restrict__ Z2)
{
    __shared__ float Al[2][16][64];   // x tile [c][l]
    __shared__ float Bl[2][16][68];   // Win tile [c][d] (padded)
    const int tid = threadIdx.x;
    const int ty = tid >> 4, tx = tid & 15;
    const int l0 = blockIdx.x * 64;
    const int d0 = blockIdx.y * 64;
    const int n  = blockIdx.z;
    const float* xn = x + (size_t)n * C_ * L_;

    const int ac = tid >> 4, alq = tid & 15;
    const int bd = tid >> 2, bq  = tid & 3;

    float acc[4][4];
    #pragma unroll
    for (int i = 0; i < 4; ++i)
        #pragma unroll
        for (int j = 0; j < 4; ++j) acc[i][j] = 0.0f;

    auto stage = [&](int cc, int buf) {
        float4 av = *(const float4*)(xn + (size_t)(cc*16 + ac) * L_ + l0 + alq*4);
        *(float4*)&Al[buf][ac][alq*4] = av;
        float4 bv = *(const float4*)(Win + (size_t)(d0 + bd) * C_ + cc*16 + bq*4);
        Bl[buf][bq*4+0][bd] = bv.x; Bl[buf][bq*4+1][bd] = bv.y;
        Bl[buf][bq*4+2][bd] = bv.z; Bl[buf][bq*4+3][bd] = bv.w;
    };

    stage(0, 0);
    for (int cc = 0; cc < 32; ++cc) {
        __syncthreads();
        if (cc + 1 < 32) stage(cc + 1, (cc + 1) & 1);
        const int buf = cc & 1;
        #pragma unroll
        for (int k = 0; k < 16; ++k) {
            float4 a = *(const float4*)&Al[buf][k][ty*4];
            float4 b = *(const float4*)&Bl[buf][k][tx*4];
            acc[0][0]=fmaf(a.x,b.x,acc[0][0]); acc[0][1]=fmaf(a.x,b.y,acc[0][1]);
            acc[0][2]=fmaf(a.x,b.z,acc[0][2]); acc[0][3]=fmaf(a.x,b.w,acc[0][3]);
            acc[1][0]=fmaf(a.y,b.x,acc[1][0]); acc[1][1]=fmaf(a.y,b.y,acc[1][1]);
            acc[1][2]=fmaf(a.y,b.z,acc[1][2]); acc[1][3]=fmaf(a.y,b.w,acc[1][3]);
            acc[2][0]=fmaf(a.z,b.x,acc[2][0]); acc[2][1]=fmaf(a.z,b.y,acc[2][1]);
            acc[2][2]=fmaf(a.z,b.z,acc[2][2]); acc[2][3]=fmaf(a.z,b.w,acc[2][3]);
            acc[3][0]=fmaf(a.w,b.x,acc[3][0]); acc[3][1]=fmaf(a.w,b.y,acc[3][1]);
            acc[3][2]=fmaf(a.w,b.z,acc[3][2]); acc[3][3]=fmaf(a.w,b.w,acc[3][3]);
        }
    }
    float4 bias = *(const float4*)(inb + d0 + tx*4);
    #pragma unroll
    for (int i = 0; i < 4; ++i) {
        float4 o;
        o.x = acc[i][0] + bias.x; o.y = acc[i][1] + bias.y;
        o.z = acc[i][2] + bias.z; o.w = acc[i][3] + bias.w;
        const size_t row = (size_t)(n*L_ + l0 + ty*4 + i);
        *(float4*)&Zt[row * D_ + d0 + tx*4] = o;
        ushort4 h, lo;
        h.x = f2bf(o.x); h.y = f2bf(o.y); h.z = f2bf(o.z); h.w = f2bf(o.w);
        lo.x = f2bf(o.x - bf2f(h.x)); lo.y = f2bf(o.y - bf2f(h.y));
        lo.z = f2bf(o.z - bf2f(h.z)); lo.w = f2bf(o.w - bf2f(h.w));
        *(ushort4*)&Z2[row * 512 + d0 + tx*4]       = h;
        *(ushort4*)&Z2[row * 512 + 256 + d0 + tx*4] = lo;
    }
}

// ---------------------------------------------------------------------------
// P GEMM: P[k][c] = sum_d cb[k][d] * Wout[c][d]    (8192 x 512 x 256)
// ---------------------------------------------------------------------------
__global__ __launch_bounds__(256) void pmat_kernel(
    const float* __restrict__ cb, const float* __restrict__ Wout,
    float* __restrict__ P)
{
    __shared__ float Al[2][16][68];
    __shared__ float Bl[2][16][68];
    const int tid = threadIdx.x;
    const int ty = tid >> 4, tx = tid & 15;
    const int k0 = blockIdx.x * 64;
    const int c0 = blockIdx.y * 64;
    const int ar = tid >> 2, aq = tid & 3;

    float acc[4][4];
    #pragma unroll
    for (int i = 0; i < 4; ++i)
        #pragma unroll
        for (int j = 0; j < 4; ++j) acc[i][j] = 0.0f;

    auto stage = [&](int dc, int buf) {
        float4 av = *(const float4*)(cb + (size_t)(k0 + ar) * D_ + dc*16 + aq*4);
        Al[buf][aq*4+0][ar] = av.x; Al[buf][aq*4+1][ar] = av.y;
        Al[buf][aq*4+2][ar] = av.z; Al[buf][aq*4+3][ar] = av.w;
        float4 bv = *(const float4*)(Wout + (size_t)(c0 + ar) * D_ + dc*16 + aq*4);
        Bl[buf][aq*4+0][ar] = bv.x; Bl[buf][aq*4+1][ar] = bv.y;
        Bl[buf][aq*4+2][ar] = bv.z; Bl[buf][aq*4+3][ar] = bv.w;
    };

    stage(0, 0);
    for (int dc = 0; dc < 16; ++dc) {
        __syncthreads();
        if (dc + 1 < 16) stage(dc + 1, (dc + 1) & 1);
        const int buf = dc & 1;
        #pragma unroll
        for (int k = 0; k < 16; ++k) {
            float4 a = *(const float4*)&Al[buf][k][ty*4];
            float4 b = *(const float4*)&Bl[buf][k][tx*4];
            acc[0][0]=fmaf(a.x,b.x,acc[0][0]); acc[0][1]=fmaf(a.x,b.y,acc[0][1]);
            acc[0][2]=fmaf(a.x,b.z,acc[0][2]); acc[0][3]=fmaf(a.x,b.w,acc[0][3]);
            acc[1][0]=fmaf(a.y,b.x,acc[1][0]); acc[1][1]=fmaf(a.y,b.y,acc[1][1]);
            acc[1][2]=fmaf(a.y,b.z,acc[1][2]); acc[1][3]=fmaf(a.y,b.w,acc[1][3]);
            acc[2][0]=fmaf(a.z,b.x,acc[2][0]); acc[2][1]=fmaf(a.z,b.y,acc[2][1]);
            acc[2][2]=fmaf(a.z,b.z,acc[2][2]); acc[2][3]=fmaf(a.z,b.w,acc[2][3]);
            acc[3][0]=fmaf(a.w,b.x,acc[3][0]); acc[3][1]=fmaf(a.w,b.y,acc[3][1]);
            acc[3][2]=fmaf(a.w,b.z,acc[3][2]); acc[3][3]=fmaf(a.w,b.w,acc[3][3]);
        }
    }
    #pragma unroll
    for (int i = 0; i < 4; ++i) {
        float4 o;
        o.x = acc[i][0]; o.y = acc[i][1]; o.z = acc[i][2]; o.w = acc[i][3];
        *(float4*)&P[(size_t)(k0 + ty*4 + i) * C_ + c0 + tx*4] = o;
    }
}

// ---------------------------------------------------------------------------
// sim (MFMA): v5 -- v4 pipeline + VOLATILE-pinned A fragments.
// v4 post-mortem: VGPR=88 (need >=150 for af+bg) proved af was STILL not
// register-resident; all of v1/v3/v4 land at ~555-570us because each streams
// ~16KB/wave/chunk through L2 (A or B), hitting an effective pure-L2 wall
// of ~2 TB/s/XCD.  The "+v" asm pin failed (allocator spilled/remat'd).
// v5: af loaded through a VOLATILE pointer -- volatile loads cannot be
// rematerialized or re-executed, so the 16 values MUST stay live in VGPRs.
// Verification signal: VGPR_Count ~150-190.  Also: sched_barrier(0) after
// s_barrier (llvm.amdgcn.s.barrier is not a memory fence; prevents ds_read
// hoisting above the barrier -- correctness hygiene).
// Pipeline unchanged from v4: 4-buffer LDS rotation, counted vmcnt(8),
// one barrier per chunk; grid 1024 (256 mtiles x 4 ks), 2 blocks/CU.
// ---------------------------------------------------------------------------
__global__ __launch_bounds__(256, 2) void sim_kernel(
    const unsigned short* __restrict__ Z2, const unsigned short* __restrict__ CB2F,
    float* __restrict__ Part)
{
    __shared__ char lds[4][16384];
    const int tid = threadIdx.x;
    const int w = tid >> 6, l = tid & 63;
    const int bid = blockIdx.x;
    const int ks = bid & 3;             // code range (constant per XCD)
    const int mtile = bid >> 2;         // 0..255
    const int m0 = mtile * 64 + w * 16;
    const int n0 = ks * 2048;
    const char* Bchunk = (const char*)CB2F + (size_t)(n0 >> 4) * 16384;

    // A fragments: lane holds A[m][k], m = l&15, klocal = (l>>4)*8 + j.
    // VOLATILE loads: cannot be remat'd/duplicated -> af stays in 64 VGPRs.
    const char* Abase = (const char*)Z2 + (size_t)(m0 + (l & 15)) * 1024
                        + ((l >> 4) * 16);
    bf16x8 af[16];
    #pragma unroll
    for (int f = 0; f < 8; ++f) {
        af[f]     = *(const volatile bf16x8*)(Abase + f * 64);          // hi
        af[f + 8] = *(const volatile bf16x8*)(Abase + 512 + f * 64);    // lo
    }
    // Drain A loads so the vmcnt stream below contains ONLY staging loads.
    asm volatile("s_waitcnt vmcnt(0)" ::: "memory");

    float bv1[4], bv2[4]; int bi1[4], bi2[4];
    #pragma unroll
    for (int t = 0; t < 4; ++t) {
        bv1[t] = -3.0e38f; bv2[t] = -3.0e38f;
        bi1[t] = 0x7FFFFFFF; bi2[t] = 0x7FFFFFFF;
    }

    // stage chunk ch into lds[ch&3]; each wave copies its 4KB quarter
    // (4 gload_lds16 per wave -> vmcnt +4)
    auto stage = [&](int ch) {
        const char* s = Bchunk + (size_t)ch * 16384 + (size_t)w * 4096
                        + (size_t)l * 16;
        char* d = &lds[ch & 3][w * 4096];
        gload_lds16(s,        d);
        gload_lds16(s + 1024, d + 1024);
        gload_lds16(s + 2048, d + 2048);
        gload_lds16(s + 3072, d + 3072);
    };

    stage(0); stage(1); stage(2);    // 12 outstanding/wave

    for (int c = 0; c < 128; ++c) {
        // wait for chunk c's 4 loads (keep up to 8 newer in flight)
        if (c <= 125)      { asm volatile("s_waitcnt vmcnt(8)" ::: "memory"); }
        else if (c == 126) { asm volatile("s_waitcnt vmcnt(4)" ::: "memory"); }
        else               { asm volatile("s_waitcnt vmcnt(0)" ::: "memory"); }
        __builtin_amdgcn_s_barrier();   // all waves' quarters of chunk c landed
        __builtin_amdgcn_sched_barrier(0);  // no ds_read hoists above barrier
        if (c + 3 < 128) stage(c + 3);  // refill pipeline (writes buf[(c-1)&3])

        const char* p = &lds[c & 3][l * 16];
        bf16x8 bg[16];
        #pragma unroll
        for (int f = 0; f < 16; ++f)
            bg[f] = *(const bf16x8*)(p + (size_t)f * 1024);

        f32x4 a0 = {0.f,0.f,0.f,0.f}, a1 = a0, a2 = a0, a3 = a0;
        #pragma unroll
        for (int f = 0; f < 8; f += 2) {
            a0 = __builtin_amdgcn_mfma_f32_16x16x32_bf16(af[f],   bg[f],   a0, 0,0,0); // hi*hi
            a1 = __builtin_amdgcn_mfma_f32_16x16x32_bf16(af[f+1], bg[f+1], a1, 0,0,0);
            a2 = __builtin_amdgcn_mfma_f32_16x16x32_bf16(af[f+8], bg[f],   a2, 0,0,0); // lo*hi
            a3 = __builtin_amdgcn_mfma_f32_16x16x32_bf16(af[f+9], bg[f+1], a3, 0,0,0);
            a0 = __builtin_amdgcn_mfma_f32_16x16x32_bf16(af[f],   bg[f+8], a0, 0,0,0); // hi*lo
            a1 = __builtin_amdgcn_mfma_f32_16x16x32_bf16(af[f+1], bg[f+9], a1, 0,0,0);
        }
        f32x4 s01 = a0 + a1, s23 = a2 + a3;
        f32x4 s = s01 + s23;

        const int colbase = n0 + c * 16 + (l & 15);
        #pragma unroll
        for (int t = 0; t < 4; ++t)
            push2(bv1[t], bi1[t], bv2[t], bi2[t], s[t], colbase);
        // no trailing barrier: next iteration's vmcnt-wait + barrier gates
    }

    // merge across the 16 col-lanes (xor masks 1,2,4,8); C/D layout:
    // col = lane&15, row = (lane>>4)*4 + reg
    #pragma unroll
    for (int t = 0; t < 4; ++t) {
        float v1 = bv1[t], v2 = bv2[t];
        int   i1 = bi1[t], i2 = bi2[t];
        #pragma unroll
        for (int mask = 1; mask < 16; mask <<= 1) {
            float ov1 = __shfl_xor(v1, mask, 64);
            int   oi1 = __shfl_xor(i1, mask, 64);
            float ov2 = __shfl_xor(v2, mask, 64);
            int   oi2 = __shfl_xor(i2, mask, 64);
            push2(v1, i1, v2, i2, ov1, oi1);
            push2(v1, i1, v2, i2, ov2, oi2);
        }
        if ((l & 15) == 0) {
            const int row = m0 + (l >> 4) * 4 + t;
            float4 o;
            o.x = v1; o.y = __int_as_float(i1);
            o.z = v2; o.w = __int_as_float(i2);
            *(float4*)&Part[((size_t)row * 4 + ks) * 4] = o;
        }
    }
}

// ---------------------------------------------------------------------------
// argmax reduce + exact fp32 recheck: merge 4 ks-partials/row -> top2,
// recompute both candidate dots in fp32, pick winner (tie -> smaller index).
// grid 4096 x 256 (wave per row).
// ---------------------------------------------------------------------------
__global__ __launch_bounds__(256) void argmax_kernel(
    const float* __restrict__ Part, const float* __restrict__ Zt,
    const float* __restrict__ cb, const float* __restrict__ invn,
    int* __restrict__ idxout, float* __restrict__ fidxout)
{
    const int w = threadIdx.x >> 6, l = threadIdx.x & 63;
    const int row = blockIdx.x * 4 + w;
    float v1 = -3.0e38f, v2 = -3.0e38f;
    int   i1 = 0x7FFFFFFF, i2 = 0x7FFFFFFF;
    if (l < 4) {
        float4 p = *(const float4*)&Part[((size_t)row * 4 + l) * 4];
        v1 = p.x; i1 = __float_as_int(p.y);
        v2 = p.z; i2 = __float_as_int(p.w);
    }
    #pragma unroll
    for (int mask = 1; mask < 4; mask <<= 1) {
        float ov1 = __shfl_xor(v1, mask, 64);
        int   oi1 = __shfl_xor(i1, mask, 64);
        float ov2 = __shfl_xor(v2, mask, 64);
        int   oi2 = __shfl_xor(i2, mask, 64);
        push2(v1, i1, v2, i2, ov1, oi1);
        push2(v1, i1, v2, i2, ov2, oi2);
    }
    // broadcast lane 0's top2 to all lanes
    v1 = __shfl(v1, 0, 64); i1 = __shfl(i1, 0, 64);
    v2 = __shfl(v2, 0, 64); i2 = __shfl(i2, 0, 64);
    // exact fp32 dots for the two candidates
    const float* z  = Zt + (size_t)row * D_;
    float4 zv = *(const float4*)(z + l*4);
    float4 a  = *(const float4*)(cb + (size_t)i1 * D_ + l*4);
    float4 b  = *(const float4*)(cb + (size_t)i2 * D_ + l*4);
    float s1 = zv.x*a.x + zv.y*a.y + zv.z*a.z + zv.w*a.w;
    float s2 = zv.x*b.x + zv.y*b.y + zv.z*b.z + zv.w*b.w;
    s1 = waveReduceSum64(s1);
    s2 = waveReduceSum64(s2);
    float e1 = s1 * invn[i1];
    float e2 = s2 * invn[i2];
    int win = (e2 > e1 || (e2 == e1 && i2 < i1)) ? i2 : i1;
    if (l == 0) { idxout[row] = win; fidxout[row] = (float)win; }
}

// ---------------------------------------------------------------------------
// losses: S[n] = sum_{l,d} (cb[idx[n,l]][d] - Zt[n*L+l][d])^2
// ---------------------------------------------------------------------------
__global__ __launch_bounds__(256) void loss_kernel(
    const float* __restrict__ Zt, const float* __restrict__ cb,
    const int* __restrict__ idx, float* __restrict__ lossacc)
{
    __shared__ float red[4];
    const int tid = threadIdx.x;
    const int r = blockIdx.x * 64 + (tid >> 2);
    const int q = tid & 3;
    const int n = r >> 12;
    const int code = idx[r];
    const float* zp = Zt + (size_t)r * D_ + q * 64;
    const float* cp = cb + (size_t)code * D_ + q * 64;
    float s = 0.0f;
    #pragma unroll
    for (int it = 0; it < 16; ++it) {
        float4 a = *(const float4*)(zp + it*4);
        float4 c = *(const float4*)(cp + it*4);
        float dx = c.x - a.x, dy = c.y - a.y, dz = c.z - a.z, dw = c.w - a.w;
        s += dx*dx + dy*dy + dz*dz + dw*dw;
    }
    s = waveReduceSum64(s);
    if ((tid & 63) == 0) red[tid >> 6] = s;
    __syncthreads();
    if (tid == 0) atomicAdd(&lossacc[n], red[0] + red[1] + red[2] + red[3]);
}

// ---------------------------------------------------------------------------
// y gather: y[n][c][l] = P[idx[n,l]][c] + out_b[c]
// ---------------------------------------------------------------------------
__global__ __launch_bounds__(256) void y_kernel(
    const float* __restrict__ P, const int* __restrict__ idx,
    const float* __restrict__ outb, float* __restrict__ y)
{
    __shared__ float bias[128];
    const int t = threadIdx.x;
    const int c0 = blockIdx.y * 128;
    const int n = blockIdx.z;
    const int l = blockIdx.x * 256 + t;
    if (t < 128) bias[t] = outb[c0 + t];
    __syncthreads();
    const int code = idx[n * L_ + l];
    const float* prow = P + (size_t)code * C_ + c0;
    float* yb = y + ((size_t)n * C_ + c0) * L_ + l;
    #pragma unroll 4
    for (int c = 0; c < 128; ++c) {
        yb[(size_t)c * L_] = prow[c] + bias[c];
    }
}

__global__ __launch_bounds__(64) void fin_kernel(
    const float* __restrict__ lossacc, float* __restrict__ out)
{
    const int t = threadIdx.x;
    if (t < 8) out[t] = lossacc[t & 3] * (1.0f / (float)(D_ * L_));
}

extern "C" void kernel_launch(void* const* d_in, const int* in_sizes, int n_in,
                              void* d_out, int out_size, void* d_ws, size_t ws_size,
                              hipStream_t stream) {
    (void)in_sizes; (void)n_in; (void)out_size; (void)ws_size;
    const float* x     = (const float*)d_in[0];
    const float* in_v  = (const float*)d_in[1];
    const float* in_g  = (const float*)d_in[2];
    const float* in_b  = (const float*)d_in[3];
    const float* out_v = (const float*)d_in[4];
    const float* out_g = (const float*)d_in[5];
    const float* out_b = (const float*)d_in[6];
    const float* cb    = (const float*)d_in[7];
    float* out = (float*)d_out;
    float* ws  = (float*)d_ws;

    float*          Zt     = ws + WS_ZT;
    float*          P      = ws + WS_P;
    unsigned short* Z2     = (unsigned short*)(ws + WS_Z2);
    unsigned short* CB2F   = (unsigned short*)(ws + WS_CB2);
    float*          Part   = ws + WS_PART;
    float*          Win    = ws + WS_WIN;
    float*          Wout   = ws + WS_WOUT;
    float*          invn   = ws + WS_INVN;
    int*            idx    = (int*)(ws + WS_IDX);
    float*          lossac = ws + WS_LOSS;

    prep_kernel<<<dim3(D_ + C_), 64, 0, stream>>>(in_v, in_g, out_v, out_g,
                                                  Win, Wout, lossac);
    cb2_kernel<<<dim3(K_), 64, 0, stream>>>(cb, invn);
    cb2f_kernel<<<dim3(512), 256, 0, stream>>>(cb, invn, CB2F);
    ze_kernel<<<dim3(64, 4, 4), 256, 0, stream>>>(x, Win, in_b, Zt, Z2);
    pmat_kernel<<<dim3(128, 8), 256, 0, stream>>>(cb, Wout, P);
    sim_kernel<<<dim3(1024), 256, 0, stream>>>(Z2, CB2F, Part);
    argmax_kernel<<<dim3(4096), 256, 0, stream>>>(Part, Zt, cb, invn,
                                                  idx, out + OUT_IDX_OFF);
    loss_kernel<<<dim3(256), 256, 0, stream>>>(Zt, cb, idx, lossac);
    y_kernel<<<dim3(16, 4, 4), 256, 0, stream>>>(P, idx, out_b, out);
    fin_kernel<<<dim3(1), 64, 0, stream>>>(lossac, out + OUT_CB_OFF);
}

// Round 5
// 707.316 us; speedup vs baseline: 1.0682x; 1.0682x over previous
//
#include <hip/hip_runtime.h>
#include <math.h>

// Problem dims
#define N_ 4
#define C_ 512
#define L_ 4096
#define D_ 256
#define K_ 8192
#define NL_ 16384           // N_*L_

// d_out layout (float32 flat): y | code_index(as float) | cb_loss | cm_loss
#define OUT_IDX_OFF (N_*C_*L_)          // 8388608
#define OUT_CB_OFF  (OUT_IDX_OFF + NL_) // 8404992

// ws layout (float units).
#define WS_ZT   0                                  // Zt[16384][256] f32
#define WS_P    (WS_ZT + (size_t)NL_*D_)           // P[8192][512] f32
#define WS_Z2   (WS_P + (size_t)K_*C_)             // Z2[16384][512] bf16 (hi|lo row-major)
#define WS_CB2  (WS_Z2 + (size_t)NL_*D_)           // CB2F[512 c16][16 frag][64 lane][8] bf16
#define WS_PART (WS_CB2 + (size_t)K_*D_)           // Part[16384][4 ks][4] f32 top2 partials
#define WS_WIN  (WS_PART + (size_t)NL_*64*4)       // W_in[256][512]
#define WS_WOUT (WS_WIN + (size_t)D_*C_)           // W_out[512][256]
#define WS_INVN (WS_WOUT + (size_t)C_*D_)          // inv codebook norms [8192]
#define WS_IDX  (WS_INVN + (size_t)K_)             // idx[16384] (int)
#define WS_LOSS (WS_IDX + (size_t)NL_)             // loss accum [4]

typedef __bf16 bf16x8 __attribute__((ext_vector_type(8)));
typedef float  f32x4  __attribute__((ext_vector_type(4)));
typedef unsigned int u32;

__device__ __forceinline__ unsigned short f2bf(float f) {   // round-nearest-even
    u32 u = __float_as_uint(f);
    u32 r = (u + 0x7fffu + ((u >> 16) & 1u)) >> 16;
    return (unsigned short)r;
}
__device__ __forceinline__ float bf2f(unsigned short h) {
    return __uint_as_float(((u32)h) << 16);
}

__device__ __forceinline__ float waveReduceSum64(float s) {
    #pragma unroll
    for (int off = 32; off; off >>= 1) s += __shfl_xor(s, off, 64);
    return s;
}

// prefer (av,ai) over (bv,bi)?  larger value wins; tie -> smaller index
__device__ __forceinline__ bool pref(float av, int ai, float bv, int bi) {
    return (av > bv) || (av == bv && ai < bi);
}
// push candidate (wv,wi) into sorted top2 (v1,i1,v2,i2)
__device__ __forceinline__ void push2(float& v1, int& i1, float& v2, int& i2,
                                      float wv, int wi) {
    if (pref(wv, wi, v1, i1)) { v2 = v1; i2 = i1; v1 = wv; i1 = wi; }
    else if (pref(wv, wi, v2, i2)) { v2 = wv; i2 = wi; }
}

// async global->LDS copy, 16B per lane; lds dest must be wave-uniform base
__device__ __forceinline__ void gload_lds16(const void* g, void* l) {
    __builtin_amdgcn_global_load_lds(
        (const __attribute__((address_space(1))) void*)g,
        (__attribute__((address_space(3))) void*)l,
        16, 0, 0);
}

// ---------------------------------------------------------------------------
// prep: W_in = g*v/||v||, W_out likewise, zero loss accum.
// ---------------------------------------------------------------------------
__global__ __launch_bounds__(64) void prep_kernel(
    const float* __restrict__ in_v, const float* __restrict__ in_g,
    const float* __restrict__ out_v, const float* __restrict__ out_g,
    float* __restrict__ Win, float* __restrict__ Wout,
    float* __restrict__ lossacc)
{
    const int b = blockIdx.x;
    const int t = threadIdx.x;
    if (b == 0 && t < N_) lossacc[t] = 0.0f;
    if (b < D_) {
        const float* v = in_v + (size_t)b * C_;
        float4 a0 = *(const float4*)(v + t * 4);
        float4 a1 = *(const float4*)(v + 256 + t * 4);
        float s = a0.x*a0.x + a0.y*a0.y + a0.z*a0.z + a0.w*a0.w
                + a1.x*a1.x + a1.y*a1.y + a1.z*a1.z + a1.w*a1.w;
        s = waveReduceSum64(s);
        float scale = in_g[b] / sqrtf(s);
        float* w = Win + (size_t)b * C_;
        float4 o0, o1;
        o0.x=a0.x*scale; o0.y=a0.y*scale; o0.z=a0.z*scale; o0.w=a0.w*scale;
        o1.x=a1.x*scale; o1.y=a1.y*scale; o1.z=a1.z*scale; o1.w=a1.w*scale;
        *(float4*)(w + t*4) = o0;
        *(float4*)(w + 256 + t*4) = o1;
    } else {
        const int r = b - D_;
        const float* v = out_v + (size_t)r * D_;
        float4 a0 = *(const float4*)(v + t * 4);
        float s = a0.x*a0.x + a0.y*a0.y + a0.z*a0.z + a0.w*a0.w;
        s = waveReduceSum64(s);
        float scale = out_g[r] / sqrtf(s);
        float4 o0;
        o0.x=a0.x*scale; o0.y=a0.y*scale; o0.z=a0.z*scale; o0.w=a0.w*scale;
        *(float4*)(Wout + (size_t)r * D_ + t*4) = o0;
    }
}

// ---------------------------------------------------------------------------
// cb2: invn[k] = 1/max(||cb_k||,eps).  grid 8192 x 64
// ---------------------------------------------------------------------------
__global__ __launch_bounds__(64) void cb2_kernel(
    const float* __restrict__ cb, float* __restrict__ invn)
{
    const int k = blockIdx.x;
    const int t = threadIdx.x;
    float4 v = *(const float4*)(cb + (size_t)k * D_ + t * 4);
    float s = v.x*v.x + v.y*v.y + v.z*v.z + v.w*v.w;
    s = waveReduceSum64(s);
    if (t == 0) invn[k] = 1.0f / fmaxf(sqrtf(s), 1e-8f);
}

// ---------------------------------------------------------------------------
// cb2f: build B-fragment-ordered split codebook.
// Layout: frag(c16, kc) = 1 KB at ((c16*16 + kc)*64 lanes)*8 shorts.
// MFMA B-operand lane map (16x16x32): lane = (klocal>>3)*16 + n, j = klocal&7.
// kc 0..7: hi(d = kc*32 + klocal), scaled by invn; kc 8..15: lo of same d.
// grid 512 x 256.  thread t: kc = t>>4, n = t&15, covers d-range (kc&7)*32..+31.
// ---------------------------------------------------------------------------
__global__ __launch_bounds__(256) void cb2f_kernel(
    const float* __restrict__ cb, const float* __restrict__ invn,
    unsigned short* __restrict__ CB2F)
{
    const int c16 = blockIdx.x;
    const int t = threadIdx.x;
    const int kc = t >> 4, nl = t & 15;
    const int code = c16 * 16 + nl;
    const float inv = invn[code];
    const float* src = cb + (size_t)code * D_ + (kc & 7) * 32;
    unsigned short* dst = CB2F + ((size_t)(c16 * 16 + kc) * 64) * 8;
    #pragma unroll
    for (int lh = 0; lh < 4; ++lh) {
        float4 x0 = *(const float4*)(src + lh * 8);
        float4 x1 = *(const float4*)(src + lh * 8 + 4);
        float f[8] = {x0.x, x0.y, x0.z, x0.w, x1.x, x1.y, x1.z, x1.w};
        unsigned short o[8];
        #pragma unroll
        for (int j = 0; j < 8; ++j) {
            float v = f[j] * inv;
            unsigned short h = f2bf(v);
            o[j] = (kc < 8) ? h : f2bf(v - bf2f(h));
        }
        unsigned short* dp = dst + (lh * 16 + nl) * 8;
        *(ushort4*)&dp[0] = make_ushort4(o[0], o[1], o[2], o[3]);
        *(ushort4*)&dp[4] = make_ushort4(o[4], o[5], o[6], o[7]);
    }
}

// ---------------------------------------------------------------------------
// z_e GEMM: Zt[n*L+l][d] = sum_c x[n][c][l]*Win[d][c] + in_b[d]; also writes
// bf16 split Z2[row] = [hi | lo] row-major.
// ---------------------------------------------------------------------------
__global__ __launch_bounds__(256) void ze_kernel(
    const float* __restrict__ x, const float* __restrict__ Win,
    const float* __restrict__ inb, float* __restrict__ Zt,
    unsigned short* __restrict__ Z2)
{
    __shared__ float Al[2][16][64];   // x tile [c][l]
    __shared__ float Bl[2][16][68];   // Win tile [c][d] (padded)
    const int tid = threadIdx.x;
    const int ty = tid >> 4, tx = tid & 15;
    const int l0 = blockIdx.x * 64;
    const int d0 = blockIdx.y * 64;
    const int n  = blockIdx.z;
    const float* xn = x + (size_t)n * C_ * L_;

    const int ac = tid >> 4, alq = tid & 15;
    const int bd = tid >> 2, bq  = tid & 3;

    float acc[4][4];
    #pragma unroll
    for (int i = 0; i < 4; ++i)
        #pragma unroll
        for (int j = 0; j < 4; ++j) acc[i][j] = 0.0f;

    auto stage = [&](int cc, int buf) {
        float4 av = *(const float4*)(xn + (size_t)(cc*16 + ac) * L_ + l0 + alq*4);
        *(float4*)&Al[buf][ac][alq*4] = av;
        float4 bv = *(const float4*)(Win + (size_t)(d0 + bd) * C_ + cc*16 + bq*4);
        Bl[buf][bq*4+0][bd] = bv.x; Bl[buf][bq*4+1][bd] = bv.y;
        Bl[buf][bq*4+2][bd] = bv.z; Bl[buf][bq*4+3][bd] = bv.w;
    };

    stage(0, 0);
    for (int cc = 0; cc < 32; ++cc) {
        __syncthreads();
        if (cc + 1 < 32) stage(cc + 1, (cc + 1) & 1);
        const int buf = cc & 1;
        #pragma unroll
        for (int k = 0; k < 16; ++k) {
            float4 a = *(const float4*)&Al[buf][k][ty*4];
            float4 b = *(const float4*)&Bl[buf][k][tx*4];
            acc[0][0]=fmaf(a.x,b.x,acc[0][0]); acc[0][1]=fmaf(a.x,b.y,acc[0][1]);
            acc[0][2]=fmaf(a.x,b.z,acc[0][2]); acc[0][3]=fmaf(a.x,b.w,acc[0][3]);
            acc[1][0]=fmaf(a.y,b.x,acc[1][0]); acc[1][1]=fmaf(a.y,b.y,acc[1][1]);
            acc[1][2]=fmaf(a.y,b.z,acc[1][2]); acc[1][3]=fmaf(a.y,b.w,acc[1][3]);
            acc[2][0]=fmaf(a.z,b.x,acc[2][0]); acc[2][1]=fmaf(a.z,b.y,acc[2][1]);
            acc[2][2]=fmaf(a.z,b.z,acc[2][2]); acc[2][3]=fmaf(a.z,b.w,acc[2][3]);
            acc[3][0]=fmaf(a.w,b.x,acc[3][0]); acc[3][1]=fmaf(a.w,b.y,acc[3][1]);
            acc[3][2]=fmaf(a.w,b.z,acc[3][2]); acc[3][3]=fmaf(a.w,b.w,acc[3][3]);
        }
    }
    float4 bias = *(const float4*)(inb + d0 + tx*4);
    #pragma unroll
    for (int i = 0; i < 4; ++i) {
        float4 o;
        o.x = acc[i][0] + bias.x; o.y = acc[i][1] + bias.y;
        o.z = acc[i][2] + bias.z; o.w = acc[i][3] + bias.w;
        const size_t row = (size_t)(n*L_ + l0 + ty*4 + i);
        *(float4*)&Zt[row * D_ + d0 + tx*4] = o;
        ushort4 h, lo;
        h.x = f2bf(o.x); h.y = f2bf(o.y); h.z = f2bf(o.z); h.w = f2bf(o.w);
        lo.x = f2bf(o.x - bf2f(h.x)); lo.y = f2bf(o.y - bf2f(h.y));
        lo.z = f2bf(o.z - bf2f(h.z)); lo.w = f2bf(o.w - bf2f(h.w));
        *(ushort4*)&Z2[row * 512 + d0 + tx*4]       = h;
        *(ushort4*)&Z2[row * 512 + 256 + d0 + tx*4] = lo;
    }
}

// ---------------------------------------------------------------------------
// P GEMM: P[k][c] = sum_d cb[k][d] * Wout[c][d]    (8192 x 512 x 256)
// ---------------------------------------------------------------------------
__global__ __launch_bounds__(256) void pmat_kernel(
    const float* __restrict__ cb, const float* __restrict__ Wout,
    float* __restrict__ P)
{
    __shared__ float Al[2][16][68];
    __shared__ float Bl[2][16][68];
    const int tid = threadIdx.x;
    const int ty = tid >> 4, tx = tid & 15;
    const int k0 = blockIdx.x * 64;
    const int c0 = blockIdx.y * 64;
    const int ar = tid >> 2, aq = tid & 3;

    float acc[4][4];
    #pragma unroll
    for (int i = 0; i < 4; ++i)
        #pragma unroll
        for (int j = 0; j < 4; ++j) acc[i][j] = 0.0f;

    auto stage = [&](int dc, int buf) {
        float4 av = *(const float4*)(cb + (size_t)(k0 + ar) * D_ + dc*16 + aq*4);
        Al[buf][aq*4+0][ar] = av.x; Al[buf][aq*4+1][ar] = av.y;
        Al[buf][aq*4+2][ar] = av.z; Al[buf][aq*4+3][ar] = av.w;
        float4 bv = *(const float4*)(Wout + (size_t)(c0 + ar) * D_ + dc*16 + aq*4);
        Bl[buf][aq*4+0][ar] = bv.x; Bl[buf][aq*4+1][ar] = bv.y;
        Bl[buf][aq*4+2][ar] = bv.z; Bl[buf][aq*4+3][ar] = bv.w;
    };

    stage(0, 0);
    for (int dc = 0; dc < 16; ++dc) {
        __syncthreads();
        if (dc + 1 < 16) stage(dc + 1, (dc + 1) & 1);
        const int buf = dc & 1;
        #pragma unroll
        for (int k = 0; k < 16; ++k) {
            float4 a = *(const float4*)&Al[buf][k][ty*4];
            float4 b = *(const float4*)&Bl[buf][k][tx*4];
            acc[0][0]=fmaf(a.x,b.x,acc[0][0]); acc[0][1]=fmaf(a.x,b.y,acc[0][1]);
            acc[0][2]=fmaf(a.x,b.z,acc[0][2]); acc[0][3]=fmaf(a.x,b.w,acc[0][3]);
            acc[1][0]=fmaf(a.y,b.x,acc[1][0]); acc[1][1]=fmaf(a.y,b.y,acc[1][1]);
            acc[1][2]=fmaf(a.y,b.z,acc[1][2]); acc[1][3]=fmaf(a.y,b.w,acc[1][3]);
            acc[2][0]=fmaf(a.z,b.x,acc[2][0]); acc[2][1]=fmaf(a.z,b.y,acc[2][1]);
            acc[2][2]=fmaf(a.z,b.z,acc[2][2]); acc[2][3]=fmaf(a.z,b.w,acc[2][3]);
            acc[3][0]=fmaf(a.w,b.x,acc[3][0]); acc[3][1]=fmaf(a.w,b.y,acc[3][1]);
            acc[3][2]=fmaf(a.w,b.z,acc[3][2]); acc[3][3]=fmaf(a.w,b.w,acc[3][3]);
        }
    }
    #pragma unroll
    for (int i = 0; i < 4; ++i) {
        float4 o;
        o.x = acc[i][0]; o.y = acc[i][1]; o.z = acc[i][2]; o.w = acc[i][3];
        *(float4*)&P[(size_t)(k0 + ty*4 + i) * C_ + c0 + tx*4] = o;
    }
}

// ---------------------------------------------------------------------------
// sim (MFMA): v6 -- 32 rows/wave, B from LDS, half the chunk-periods.
// v3-v5 post-mortem: per-CU chunk-period is ~5300cy vs ~1500cy of real work;
// no pipe >16% busy -> per-period latency/sync tax dominates, and schedule
// variants (barrier style, vmcnt depth, volatile) never changed the PERIOD
// COUNT, so all were flat.  v6 halves the period count: each wave owns 32
// rows (af0+af1 = 128 VGPR, volatile-pinned), so 512 blocks instead of 1024
// cover the output; per staged 16KB chunk a wave now runs 48 MFMAs (2x the
// work per period, 2x arithmetic intensity).  B-frag regs kept low by
// explicit two-half reuse: load hi-frags bg[0..7] -> 32 MFMAs -> reload
// bg[8..15] over the same regs -> 16 MFMAs (live B = 32 VGPR).
// Staging pipeline unchanged from v4 (4 buffers, counted vmcnt(8), one
// s_barrier/chunk).  grid 512 = 128 mgroups x 4 ks; ks = bid&3 constant
// per XCD.  Verification: VGPR_Count ~210-250, no scratch (WRITE_SIZE flat).
// ---------------------------------------------------------------------------
__global__ __launch_bounds__(256, 2) void sim_kernel(
    const unsigned short* __restrict__ Z2, const unsigned short* __restrict__ CB2F,
    float* __restrict__ Part)
{
    __shared__ char lds[4][16384];
    const int tid = threadIdx.x;
    const int w = tid >> 6, l = tid & 63;
    const int bid = blockIdx.x;
    const int ks = bid & 3;             // code range (constant per XCD)
    const int mgrp = bid >> 2;          // 0..127
    const int m0 = mgrp * 128 + w * 32; // wave owns rows m0..m0+31
    const int n0 = ks * 2048;
    const char* Bchunk = (const char*)CB2F + (size_t)(n0 >> 4) * 16384;

    // A fragments: lane holds A[m][k], m = l&15, klocal = (l>>4)*8 + j.
    // VOLATILE loads: cannot be remat'd/duplicated -> 128 VGPRs stay live.
    const char* Abase0 = (const char*)Z2 + (size_t)(m0 + (l & 15)) * 1024
                         + ((l >> 4) * 16);
    const char* Abase1 = Abase0 + 16 * 1024;
    bf16x8 af0[16], af1[16];
    #pragma unroll
    for (int f = 0; f < 8; ++f) {
        af0[f]     = *(const volatile bf16x8*)(Abase0 + f * 64);        // hi rows 0-15
        af0[f + 8] = *(const volatile bf16x8*)(Abase0 + 512 + f * 64);  // lo rows 0-15
        af1[f]     = *(const volatile bf16x8*)(Abase1 + f * 64);        // hi rows 16-31
        af1[f + 8] = *(const volatile bf16x8*)(Abase1 + 512 + f * 64);  // lo rows 16-31
    }
    // Drain A loads so the vmcnt stream below contains ONLY staging loads.
    asm volatile("s_waitcnt vmcnt(0)" ::: "memory");

    float bv1[8], bv2[8]; int bi1[8], bi2[8];   // [subtile*4 + reg]
    #pragma unroll
    for (int t = 0; t < 8; ++t) {
        bv1[t] = -3.0e38f; bv2[t] = -3.0e38f;
        bi1[t] = 0x7FFFFFFF; bi2[t] = 0x7FFFFFFF;
    }

    // stage chunk ch into lds[ch&3]; each wave copies its 4KB quarter
    auto stage = [&](int ch) {
        const char* s = Bchunk + (size_t)ch * 16384 + (size_t)w * 4096
                        + (size_t)l * 16;
        char* d = &lds[ch & 3][w * 4096];
        gload_lds16(s,        d);
        gload_lds16(s + 1024, d + 1024);
        gload_lds16(s + 2048, d + 2048);
        gload_lds16(s + 3072, d + 3072);
    };

    stage(0); stage(1); stage(2);    // 12 outstanding/wave

    for (int c = 0; c < 128; ++c) {
        // wait for chunk c's 4 loads (keep up to 8 newer in flight)
        if (c <= 125)      { asm volatile("s_waitcnt vmcnt(8)" ::: "memory"); }
        else if (c == 126) { asm volatile("s_waitcnt vmcnt(4)" ::: "memory"); }
        else               { asm volatile("s_waitcnt vmcnt(0)" ::: "memory"); }
        __builtin_amdgcn_s_barrier();   // all waves' quarters of chunk c landed
        __builtin_amdgcn_sched_barrier(0);  // no ds_read hoists above barrier
        if (c + 3 < 128) stage(c + 3);  // refill pipeline (writes buf[(c-1)&3])

        const char* p = &lds[c & 3][l * 16];
        f32x4 x0 = {0.f,0.f,0.f,0.f}, x1 = x0, y0 = x0, y1 = x0;

        bf16x8 bg[8];
        // half 1: hi B-frags -> hi*hi + lo*hi for both row-subtiles (32 MFMA)
        #pragma unroll
        for (int f = 0; f < 8; ++f)
            bg[f] = *(const bf16x8*)(p + (size_t)f * 1024);
        #pragma unroll
        for (int f = 0; f < 8; f += 2) {
            x0 = __builtin_amdgcn_mfma_f32_16x16x32_bf16(af0[f],   bg[f],   x0, 0,0,0);
            y0 = __builtin_amdgcn_mfma_f32_16x16x32_bf16(af1[f],   bg[f],   y0, 0,0,0);
            x1 = __builtin_amdgcn_mfma_f32_16x16x32_bf16(af0[f+1], bg[f+1], x1, 0,0,0);
            y1 = __builtin_amdgcn_mfma_f32_16x16x32_bf16(af1[f+1], bg[f+1], y1, 0,0,0);
            x0 = __builtin_amdgcn_mfma_f32_16x16x32_bf16(af0[f+8], bg[f],   x0, 0,0,0);
            y0 = __builtin_amdgcn_mfma_f32_16x16x32_bf16(af1[f+8], bg[f],   y0, 0,0,0);
            x1 = __builtin_amdgcn_mfma_f32_16x16x32_bf16(af0[f+9], bg[f+1], x1, 0,0,0);
            y1 = __builtin_amdgcn_mfma_f32_16x16x32_bf16(af1[f+9], bg[f+1], y1, 0,0,0);
        }
        // half 2: lo B-frags (reuse bg regs) -> hi*lo for both subtiles (16 MFMA)
        #pragma unroll
        for (int f = 0; f < 8; ++f)
            bg[f] = *(const bf16x8*)(p + (size_t)(f + 8) * 1024);
        #pragma unroll
        for (int f = 0; f < 8; f += 2) {
            x0 = __builtin_amdgcn_mfma_f32_16x16x32_bf16(af0[f],   bg[f],   x0, 0,0,0);
            y0 = __builtin_amdgcn_mfma_f32_16x16x32_bf16(af1[f],   bg[f],   y0, 0,0,0);
            x1 = __builtin_amdgcn_mfma_f32_16x16x32_bf16(af0[f+1], bg[f+1], x1, 0,0,0);
            y1 = __builtin_amdgcn_mfma_f32_16x16x32_bf16(af1[f+1], bg[f+1], y1, 0,0,0);
        }
        f32x4 s0 = x0 + x1, s1 = y0 + y1;

        const int colbase = n0 + c * 16 + (l & 15);
        #pragma unroll
        for (int t = 0; t < 4; ++t) {
            push2(bv1[t],   bi1[t],   bv2[t],   bi2[t],   s0[t], colbase);
            push2(bv1[t+4], bi1[t+4], bv2[t+4], bi2[t+4], s1[t], colbase);
        }
        // no trailing barrier: next iteration's vmcnt-wait + barrier gates
    }

    // merge across the 16 col-lanes (xor masks 1,2,4,8); C/D layout:
    // col = lane&15, row = (lane>>4)*4 + reg; subtile = tt>>2.
    #pragma unroll
    for (int tt = 0; tt < 8; ++tt) {
        float v1 = bv1[tt], v2 = bv2[tt];
        int   i1 = bi1[tt], i2 = bi2[tt];
        #pragma unroll
        for (int mask = 1; mask < 16; mask <<= 1) {
            float ov1 = __shfl_xor(v1, mask, 64);
            int   oi1 = __shfl_xor(i1, mask, 64);
            float ov2 = __shfl_xor(v2, mask, 64);
            int   oi2 = __shfl_xor(i2, mask, 64);
            push2(v1, i1, v2, i2, ov1, oi1);
            push2(v1, i1, v2, i2, ov2, oi2);
        }
        if ((l & 15) == 0) {
            const int row = m0 + (tt >> 2) * 16 + (l >> 4) * 4 + (tt & 3);
            float4 o;
            o.x = v1; o.y = __int_as_float(i1);
            o.z = v2; o.w = __int_as_float(i2);
            *(float4*)&Part[((size_t)row * 4 + ks) * 4] = o;
        }
    }
}

// ---------------------------------------------------------------------------
// argmax reduce + exact fp32 recheck: merge 4 ks-partials/row -> top2,
// recompute both candidate dots in fp32, pick winner (tie -> smaller index).
// grid 4096 x 256 (wave per row).
// ---------------------------------------------------------------------------
__global__ __launch_bounds__(256) void argmax_kernel(
    const float* __restrict__ Part, const float* __restrict__ Zt,
    const float* __restrict__ cb, const float* __restrict__ invn,
    int* __restrict__ idxout, float* __restrict__ fidxout)
{
    const int w = threadIdx.x >> 6, l = threadIdx.x & 63;
    const int row = blockIdx.x * 4 + w;
    float v1 = -3.0e38f, v2 = -3.0e38f;
    int   i1 = 0x7FFFFFFF, i2 = 0x7FFFFFFF;
    if (l < 4) {
        float4 p = *(const float4*)&Part[((size_t)row * 4 + l) * 4];
        v1 = p.x; i1 = __float_as_int(p.y);
        v2 = p.z; i2 = __float_as_int(p.w);
    }
    #pragma unroll
    for (int mask = 1; mask < 4; mask <<= 1) {
        float ov1 = __shfl_xor(v1, mask, 64);
        int   oi1 = __shfl_xor(i1, mask, 64);
        float ov2 = __shfl_xor(v2, mask, 64);
        int   oi2 = __shfl_xor(i2, mask, 64);
        push2(v1, i1, v2, i2, ov1, oi1);
        push2(v1, i1, v2, i2, ov2, oi2);
    }
    // broadcast lane 0's top2 to all lanes
    v1 = __shfl(v1, 0, 64); i1 = __shfl(i1, 0, 64);
    v2 = __shfl(v2, 0, 64); i2 = __shfl(i2, 0, 64);
    // exact fp32 dots for the two candidates
    const float* z  = Zt + (size_t)row * D_;
    float4 zv = *(const float4*)(z + l*4);
    float4 a  = *(const float4*)(cb + (size_t)i1 * D_ + l*4);
    float4 b  = *(const float4*)(cb + (size_t)i2 * D_ + l*4);
    float s1 = zv.x*a.x + zv.y*a.y + zv.z*a.z + zv.w*a.w;
    float s2 = zv.x*b.x + zv.y*b.y + zv.z*b.z + zv.w*b.w;
    s1 = waveReduceSum64(s1);
    s2 = waveReduceSum64(s2);
    float e1 = s1 * invn[i1];
    float e2 = s2 * invn[i2];
    int win = (e2 > e1 || (e2 == e1 && i2 < i1)) ? i2 : i1;
    if (l == 0) { idxout[row] = win; fidxout[row] = (float)win; }
}

// ---------------------------------------------------------------------------
// losses: S[n] = sum_{l,d} (cb[idx[n,l]][d] - Zt[n*L+l][d])^2
// ---------------------------------------------------------------------------
__global__ __launch_bounds__(256) void loss_kernel(
    const float* __restrict__ Zt, const float* __restrict__ cb,
    const int* __restrict__ idx, float* __restrict__ lossacc)
{
    __shared__ float red[4];
    const int tid = threadIdx.x;
    const int r = blockIdx.x * 64 + (tid >> 2);
    const int q = tid & 3;
    const int n = r >> 12;
    const int code = idx[r];
    const float* zp = Zt + (size_t)r * D_ + q * 64;
    const float* cp = cb + (size_t)code * D_ + q * 64;
    float s = 0.0f;
    #pragma unroll
    for (int it = 0; it < 16; ++it) {
        float4 a = *(const float4*)(zp + it*4);
        float4 c = *(const float4*)(cp + it*4);
        float dx = c.x - a.x, dy = c.y - a.y, dz = c.z - a.z, dw = c.w - a.w;
        s += dx*dx + dy*dy + dz*dz + dw*dw;
    }
    s = waveReduceSum64(s);
    if ((tid & 63) == 0) red[tid >> 6] = s;
    __syncthreads();
    if (tid == 0) atomicAdd(&lossacc[n], red[0] + red[1] + red[2] + red[3]);
}

// ---------------------------------------------------------------------------
// y gather: y[n][c][l] = P[idx[n,l]][c] + out_b[c]
// ---------------------------------------------------------------------------
__global__ __launch_bounds__(256) void y_kernel(
    const float* __restrict__ P, const int* __restrict__ idx,
    const float* __restrict__ outb, float* __restrict__ y)
{
    __shared__ float bias[128];
    const int t = threadIdx.x;
    const int c0 = blockIdx.y * 128;
    const int n = blockIdx.z;
    const int l = blockIdx.x * 256 + t;
    if (t < 128) bias[t] = outb[c0 + t];
    __syncthreads();
    const int code = idx[n * L_ + l];
    const float* prow = P + (size_t)code * C_ + c0;
    float* yb = y + ((size_t)n * C_ + c0) * L_ + l;
    #pragma unroll 4
    for (int c = 0; c < 128; ++c) {
        yb[(size_t)c * L_] = prow[c] + bias[c];
    }
}

__global__ __launch_bounds__(64) void fin_kernel(
    const float* __restrict__ lossacc, float* __restrict__ out)
{
    const int t = threadIdx.x;
    if (t < 8) out[t] = lossacc[t & 3] * (1.0f / (float)(D_ * L_));
}

extern "C" void kernel_launch(void* const* d_in, const int* in_sizes, int n_in,
                              void* d_out, int out_size, void* d_ws, size_t ws_size,
                              hipStream_t stream) {
    (void)in_sizes; (void)n_in; (void)out_size; (void)ws_size;
    const float* x     = (const float*)d_in[0];
    const float* in_v  = (const float*)d_in[1];
    const float* in_g  = (const float*)d_in[2];
    const float* in_b  = (const float*)d_in[3];
    const float* out_v = (const float*)d_in[4];
    const float* out_g = (const float*)d_in[5];
    const float* out_b = (const float*)d_in[6];
    const float* cb    = (const float*)d_in[7];
    float* out = (float*)d_out;
    float* ws  = (float*)d_ws;

    float*          Zt     = ws + WS_ZT;
    float*          P      = ws + WS_P;
    unsigned short* Z2     = (unsigned short*)(ws + WS_Z2);
    unsigned short* CB2F   = (unsigned short*)(ws + WS_CB2);
    float*          Part   = ws + WS_PART;
    float*          Win    = ws + WS_WIN;
    float*          Wout   = ws + WS_WOUT;
    float*          invn   = ws + WS_INVN;
    int*            idx    = (int*)(ws + WS_IDX);
    float*          lossac = ws + WS_LOSS;

    prep_kernel<<<dim3(D_ + C_), 64, 0, stream>>>(in_v, in_g, out_v, out_g,
                                                  Win, Wout, lossac);
    cb2_kernel<<<dim3(K_), 64, 0, stream>>>(cb, invn);
    cb2f_kernel<<<dim3(512), 256, 0, stream>>>(cb, invn, CB2F);
    ze_kernel<<<dim3(64, 4, 4), 256, 0, stream>>>(x, Win, in_b, Zt, Z2);
    pmat_kernel<<<dim3(128, 8), 256, 0, stream>>>(cb, Wout, P);
    sim_kernel<<<dim3(512), 256, 0, stream>>>(Z2, CB2F, Part);
    argmax_kernel<<<dim3(4096), 256, 0, stream>>>(Part, Zt, cb, invn,
                                                  idx, out + OUT_IDX_OFF);
    loss_kernel<<<dim3(256), 256, 0, stream>>>(Zt, cb, idx, lossac);
    y_kernel<<<dim3(16, 4, 4), 256, 0, stream>>>(P, idx, out_b, out);
    fin_kernel<<<dim3(1), 64, 0, stream>>>(lossac, out + OUT_CB_OFF);
}

// Round 6
// 621.827 us; speedup vs baseline: 1.2150x; 1.1375x over previous
//
#include <hip/hip_runtime.h>
#include <math.h>

// Problem dims
#define N_ 4
#define C_ 512
#define L_ 4096
#define D_ 256
#define K_ 8192
#define NL_ 16384           // N_*L_

// d_out layout (float32 flat): y | code_index(as float) | cb_loss | cm_loss
#define OUT_IDX_OFF (N_*C_*L_)          // 8388608
#define OUT_CB_OFF  (OUT_IDX_OFF + NL_) // 8404992

// ws layout (float units).
#define WS_ZT   0                                  // Zt[16384][256] f32
#define WS_P    (WS_ZT + (size_t)NL_*D_)           // P[8192][512] f32
#define WS_Z2   (WS_P + (size_t)K_*C_)             // Z2[16384][512] bf16 (hi|lo row-major)
#define WS_CB2  (WS_Z2 + (size_t)NL_*D_)           // CB2F[512 c16][16 frag][64 lane][8] bf16
#define WS_PART (WS_CB2 + (size_t)K_*D_)           // Part[16384][4 ks][4] f32 top2 partials
#define WS_WIN  (WS_PART + (size_t)NL_*64*4)       // W_in[256][512]
#define WS_WOUT (WS_WIN + (size_t)D_*C_)           // W_out[512][256]
#define WS_INVN (WS_WOUT + (size_t)C_*D_)          // inv codebook norms [8192]
#define WS_IDX  (WS_INVN + (size_t)K_)             // idx[16384] (int)
#define WS_LOSS (WS_IDX + (size_t)NL_)             // loss accum [4]

typedef __bf16 bf16x8 __attribute__((ext_vector_type(8)));
typedef float  f32x4  __attribute__((ext_vector_type(4)));
typedef unsigned int u32;

__device__ __forceinline__ unsigned short f2bf(float f) {   // round-nearest-even
    u32 u = __float_as_uint(f);
    u32 r = (u + 0x7fffu + ((u >> 16) & 1u)) >> 16;
    return (unsigned short)r;
}
__device__ __forceinline__ float bf2f(unsigned short h) {
    return __uint_as_float(((u32)h) << 16);
}

__device__ __forceinline__ float waveReduceSum64(float s) {
    #pragma unroll
    for (int off = 32; off; off >>= 1) s += __shfl_xor(s, off, 64);
    return s;
}

// prefer (av,ai) over (bv,bi)?  larger value wins; tie -> smaller index
__device__ __forceinline__ bool pref(float av, int ai, float bv, int bi) {
    return (av > bv) || (av == bv && ai < bi);
}
// push candidate (wv,wi) into sorted top2 (v1,i1,v2,i2)
__device__ __forceinline__ void push2(float& v1, int& i1, float& v2, int& i2,
                                      float wv, int wi) {
    if (pref(wv, wi, v1, i1)) { v2 = v1; i2 = i1; v1 = wv; i1 = wi; }
    else if (pref(wv, wi, v2, i2)) { v2 = wv; i2 = wi; }
}

// async global->LDS copy, 16B per lane; lds dest must be wave-uniform base
__device__ __forceinline__ void gload_lds16(const void* g, void* l) {
    __builtin_amdgcn_global_load_lds(
        (const __attribute__((address_space(1))) void*)g,
        (__attribute__((address_space(3))) void*)l,
        16, 0, 0);
}

// ---------------------------------------------------------------------------
// prep: W_in = g*v/||v||, W_out likewise, zero loss accum.
// ---------------------------------------------------------------------------
__global__ __launch_bounds__(64) void prep_kernel(
    const float* __restrict__ in_v, const float* __restrict__ in_g,
    const float* __restrict__ out_v, const float* __restrict__ out_g,
    float* __restrict__ Win, float* __restrict__ Wout,
    float* __restrict__ lossacc)
{
    const int b = blockIdx.x;
    const int t = threadIdx.x;
    if (b == 0 && t < N_) lossacc[t] = 0.0f;
    if (b < D_) {
        const float* v = in_v + (size_t)b * C_;
        float4 a0 = *(const float4*)(v + t * 4);
        float4 a1 = *(const float4*)(v + 256 + t * 4);
        float s = a0.x*a0.x + a0.y*a0.y + a0.z*a0.z + a0.w*a0.w
                + a1.x*a1.x + a1.y*a1.y + a1.z*a1.z + a1.w*a1.w;
        s = waveReduceSum64(s);
        float scale = in_g[b] / sqrtf(s);
        float* w = Win + (size_t)b * C_;
        float4 o0, o1;
        o0.x=a0.x*scale; o0.y=a0.y*scale; o0.z=a0.z*scale; o0.w=a0.w*scale;
        o1.x=a1.x*scale; o1.y=a1.y*scale; o1.z=a1.z*scale; o1.w=a1.w*scale;
        *(float4*)(w + t*4) = o0;
        *(float4*)(w + 256 + t*4) = o1;
    } else {
        const int r = b - D_;
        const float* v = out_v + (size_t)r * D_;
        float4 a0 = *(const float4*)(v + t * 4);
        float s = a0.x*a0.x + a0.y*a0.y + a0.z*a0.z + a0.w*a0.w;
        s = waveReduceSum64(s);
        float scale = out_g[r] / sqrtf(s);
        float4 o0;
        o0.x=a0.x*scale; o0.y=a0.y*scale; o0.z=a0.z*scale; o0.w=a0.w*scale;
        *(float4*)(Wout + (size_t)r * D_ + t*4) = o0;
    }
}

// ---------------------------------------------------------------------------
// cb2: invn[k] = 1/max(||cb_k||,eps).  grid 8192 x 64
// ---------------------------------------------------------------------------
__global__ __launch_bounds__(64) void cb2_kernel(
    const float* __restrict__ cb, float* __restrict__ invn)
{
    const int k = blockIdx.x;
    const int t = threadIdx.x;
    float4 v = *(const float4*)(cb + (size_t)k * D_ + t * 4);
    float s = v.x*v.x + v.y*v.y + v.z*v.z + v.w*v.w;
    s = waveReduceSum64(s);
    if (t == 0) invn[k] = 1.0f / fmaxf(sqrtf(s), 1e-8f);
}

// ---------------------------------------------------------------------------
// cb2f: build B-fragment-ordered split codebook.
// Layout: frag(c16, kc) = 1 KB at ((c16*16 + kc)*64 lanes)*8 shorts.
// MFMA B-operand lane map (16x16x32): lane = (klocal>>3)*16 + n, j = klocal&7.
// kc 0..7: hi(d = kc*32 + klocal), scaled by invn; kc 8..15: lo of same d.
// grid 512 x 256.  thread t: kc = t>>4, n = t&15, covers d-range (kc&7)*32..+31.
// ---------------------------------------------------------------------------
__global__ __launch_bounds__(256) void cb2f_kernel(
    const float* __restrict__ cb, const float* __restrict__ invn,
    unsigned short* __restrict__ CB2F)
{
    const int c16 = blockIdx.x;
    const int t = threadIdx.x;
    const int kc = t >> 4, nl = t & 15;
    const int code = c16 * 16 + nl;
    const float inv = invn[code];
    const float* src = cb + (size_t)code * D_ + (kc & 7) * 32;
    unsigned short* dst = CB2F + ((size_t)(c16 * 16 + kc) * 64) * 8;
    #pragma unroll
    for (int lh = 0; lh < 4; ++lh) {
        float4 x0 = *(const float4*)(src + lh * 8);
        float4 x1 = *(const float4*)(src + lh * 8 + 4);
        float f[8] = {x0.x, x0.y, x0.z, x0.w, x1.x, x1.y, x1.z, x1.w};
        unsigned short o[8];
        #pragma unroll
        for (int j = 0; j < 8; ++j) {
            float v = f[j] * inv;
            unsigned short h = f2bf(v);
            o[j] = (kc < 8) ? h : f2bf(v - bf2f(h));
        }
        unsigned short* dp = dst + (lh * 16 + nl) * 8;
        *(ushort4*)&dp[0] = make_ushort4(o[0], o[1], o[2], o[3]);
        *(ushort4*)&dp[4] = make_ushort4(o[4], o[5], o[6], o[7]);
    }
}

// ---------------------------------------------------------------------------
// z_e GEMM: Zt[n*L+l][d] = sum_c x[n][c][l]*Win[d][c] + in_b[d]; also writes
// bf16 split Z2[row] = [hi | lo] row-major.
// ---------------------------------------------------------------------------
__global__ __launch_bounds__(256) void ze_kernel(
    const float* __restrict__ x, const float* __restrict__ Win,
    const float* __restrict__ inb, float* __restrict__ Zt,
    unsigned short* __restrict__ Z2)
{
    __shared__ float Al[2][16][64];   // x tile [c][l]
    __shared__ float Bl[2][16][68];   // Win tile [c][d] (padded)
    const int tid = threadIdx.x;
    const int ty = tid >> 4, tx = tid & 15;
    const int l0 = blockIdx.x * 64;
    const int d0 = blockIdx.y * 64;
    const int n  = blockIdx.z;
    const float* xn = x + (size_t)n * C_ * L_;

    const int ac = tid >> 4, alq = tid & 15;
    const int bd = tid >> 2, bq  = tid & 3;

    float acc[4][4];
    #pragma unroll
    for (int i = 0; i < 4; ++i)
        #pragma unroll
        for (int j = 0; j < 4; ++j) acc[i][j] = 0.0f;

    auto stage = [&](int cc, int buf) {
        float4 av = *(const float4*)(xn + (size_t)(cc*16 + ac) * L_ + l0 + alq*4);
        *(float4*)&Al[buf][ac][alq*4] = av;
        float4 bv = *(const float4*)(Win + (size_t)(d0 + bd) * C_ + cc*16 + bq*4);
        Bl[buf][bq*4+0][bd] = bv.x; Bl[buf][bq*4+1][bd] = bv.y;
        Bl[buf][bq*4+2][bd] = bv.z; Bl[buf][bq*4+3][bd] = bv.w;
    };

    stage(0, 0);
    for (int cc = 0; cc < 32; ++cc) {
        __syncthreads();
        if (cc + 1 < 32) stage(cc + 1, (cc + 1) & 1);
        const int buf = cc & 1;
        #pragma unroll
        for (int k = 0; k < 16; ++k) {
            float4 a = *(const float4*)&Al[buf][k][ty*4];
            float4 b = *(const float4*)&Bl[buf][k][tx*4];
            acc[0][0]=fmaf(a.x,b.x,acc[0][0]); acc[0][1]=fmaf(a.x,b.y,acc[0][1]);
            acc[0][2]=fmaf(a.x,b.z,acc[0][2]); acc[0][3]=fmaf(a.x,b.w,acc[0][3]);
            acc[1][0]=fmaf(a.y,b.x,acc[1][0]); acc[1][1]=fmaf(a.y,b.y,acc[1][1]);
            acc[1][2]=fmaf(a.y,b.z,acc[1][2]); acc[1][3]=fmaf(a.y,b.w,acc[1][3]);
            acc[2][0]=fmaf(a.z,b.x,acc[2][0]); acc[2][1]=fmaf(a.z,b.y,acc[2][1]);
            acc[2][2]=fmaf(a.z,b.z,acc[2][2]); acc[2][3]=fmaf(a.z,b.w,acc[2][3]);
            acc[3][0]=fmaf(a.w,b.x,acc[3][0]); acc[3][1]=fmaf(a.w,b.y,acc[3][1]);
            acc[3][2]=fmaf(a.w,b.z,acc[3][2]); acc[3][3]=fmaf(a.w,b.w,acc[3][3]);
        }
    }
    float4 bias = *(const float4*)(inb + d0 + tx*4);
    #pragma unroll
    for (int i = 0; i < 4; ++i) {
        float4 o;
        o.x = acc[i][0] + bias.x; o.y = acc[i][1] + bias.y;
        o.z = acc[i][2] + bias.z; o.w = acc[i][3] + bias.w;
        const size_t row = (size_t)(n*L_ + l0 + ty*4 + i);
        *(float4*)&Zt[row * D_ + d0 + tx*4] = o;
        ushort4 h, lo;
        h.x = f2bf(o.x); h.y = f2bf(o.y); h.z = f2bf(o.z); h.w = f2bf(o.w);
        lo.x = f2bf(o.x - bf2f(h.x)); lo.y = f2bf(o.y - bf2f(h.y));
        lo.z = f2bf(o.z - bf2f(h.z)); lo.w = f2bf(o.w - bf2f(h.w));
        *(ushort4*)&Z2[row * 512 + d0 + tx*4]       = h;
        *(ushort4*)&Z2[row * 512 + 256 + d0 + tx*4] = lo;
    }
}

// ---------------------------------------------------------------------------
// P GEMM: P[k][c] = sum_d cb[k][d] * Wout[c][d]    (8192 x 512 x 256)
// ---------------------------------------------------------------------------
__global__ __launch_bounds__(256) void pmat_kernel(
    const float* __restrict__ cb, const float* __restrict__ Wout,
    float* __restrict__ P)
{
    __shared__ float Al[2][16][68];
    __shared__ float Bl[2][16][68];
    const int tid = threadIdx.x;
    const int ty = tid >> 4, tx = tid & 15;
    const int k0 = blockIdx.x * 64;
    const int c0 = blockIdx.y * 64;
    const int ar = tid >> 2, aq = tid & 3;

    float acc[4][4];
    #pragma unroll
    for (int i = 0; i < 4; ++i)
        #pragma unroll
        for (int j = 0; j < 4; ++j) acc[i][j] = 0.0f;

    auto stage = [&](int dc, int buf) {
        float4 av = *(const float4*)(cb + (size_t)(k0 + ar) * D_ + dc*16 + aq*4);
        Al[buf][aq*4+0][ar] = av.x; Al[buf][aq*4+1][ar] = av.y;
        Al[buf][aq*4+2][ar] = av.z; Al[buf][aq*4+3][ar] = av.w;
        float4 bv = *(const float4*)(Wout + (size_t)(c0 + ar) * D_ + dc*16 + aq*4);
        Bl[buf][aq*4+0][ar] = bv.x; Bl[buf][aq*4+1][ar] = bv.y;
        Bl[buf][aq*4+2][ar] = bv.z; Bl[buf][aq*4+3][ar] = bv.w;
    };

    stage(0, 0);
    for (int dc = 0; dc < 16; ++dc) {
        __syncthreads();
        if (dc + 1 < 16) stage(dc + 1, (dc + 1) & 1);
        const int buf = dc & 1;
        #pragma unroll
        for (int k = 0; k < 16; ++k) {
            float4 a = *(const float4*)&Al[buf][k][ty*4];
            float4 b = *(const float4*)&Bl[buf][k][tx*4];
            acc[0][0]=fmaf(a.x,b.x,acc[0][0]); acc[0][1]=fmaf(a.x,b.y,acc[0][1]);
            acc[0][2]=fmaf(a.x,b.z,acc[0][2]); acc[0][3]=fmaf(a.x,b.w,acc[0][3]);
            acc[1][0]=fmaf(a.y,b.x,acc[1][0]); acc[1][1]=fmaf(a.y,b.y,acc[1][1]);
            acc[1][2]=fmaf(a.y,b.z,acc[1][2]); acc[1][3]=fmaf(a.y,b.w,acc[1][3]);
            acc[2][0]=fmaf(a.z,b.x,acc[2][0]); acc[2][1]=fmaf(a.z,b.y,acc[2][1]);
            acc[2][2]=fmaf(a.z,b.z,acc[2][2]); acc[2][3]=fmaf(a.z,b.w,acc[2][3]);
            acc[3][0]=fmaf(a.w,b.x,acc[3][0]); acc[3][1]=fmaf(a.w,b.y,acc[3][1]);
            acc[3][2]=fmaf(a.w,b.z,acc[3][2]); acc[3][3]=fmaf(a.w,b.w,acc[3][3]);
        }
    }
    #pragma unroll
    for (int i = 0; i < 4; ++i) {
        float4 o;
        o.x = acc[i][0]; o.y = acc[i][1]; o.z = acc[i][2]; o.w = acc[i][3];
        *(float4*)&P[(size_t)(k0 + ty*4 + i) * C_ + c0 + tx*4] = o;
    }
}

// ---------------------------------------------------------------------------
// sim (MFMA): v7 -- occupancy fix: <=128 regs/wave, 4 blocks/CU.
// v6 post-mortem: VGPR_Count shows arch-VGPRs only; af has been AGPR-resident
// all along (unified file), total regs/wave ~224-256 -> occupancy pinned at
// 2 blocks/CU (8 waves) in v1-v5; v6's 32-row config blew past 256 -> real
// per-chunk scratch spills (WRITE_SIZE 64->636MB, write-through scratch).
// The kernel is latency-bound at 8 waves/CU: per-chunk critical path
// (ds_read -> dependent MFMA chain -> push2 -> barrier) ~5000cy with only
// 2 waves/SIMD interleaving.
// v7: 16 rows/wave (af=64), bg live cut 64->8 (read 2 frags per step),
// acc 16 + top2 16 + addr ~15 => ~115 regs total.  __launch_bounds__(256,4)
// caps at 128 -> 4 waves/SIMD.  LDS 2x16KB=32KB -> 4 blocks/CU (128KB),
// 16 waves/CU, 50% occupancy, grid 1024 = one full residency, no tail.
// Simple stage-next/compute/__syncthreads double buffer: the vmcnt drain
// stall now overlaps with 3 other resident blocks.
// Verify: WRITE_SIZE ~65MB (no spill), OccupancyPercent ~44-50.
// ---------------------------------------------------------------------------
__global__ __launch_bounds__(256, 4) void sim_kernel(
    const unsigned short* __restrict__ Z2, const unsigned short* __restrict__ CB2F,
    float* __restrict__ Part)
{
    __shared__ char lds[2][16384];
    const int tid = threadIdx.x;
    const int w = tid >> 6, l = tid & 63;
    const int bid = blockIdx.x;
    const int ks = bid & 3;             // code range (constant per XCD)
    const int mtile = bid >> 2;         // 0..255
    const int m0 = mtile * 64 + w * 16;
    const int n0 = ks * 2048;
    const char* Bchunk = (const char*)CB2F + (size_t)(n0 >> 4) * 16384;

    // A fragments: lane holds A[m][k], m = l&15, klocal = (l>>4)*8 + j.
    // volatile: load exactly once (no sink/remat); 64 regs, AGPR-eligible.
    const char* Abase = (const char*)Z2 + (size_t)(m0 + (l & 15)) * 1024
                        + ((l >> 4) * 16);
    bf16x8 af[16];
    #pragma unroll
    for (int f = 0; f < 8; ++f) {
        af[f]     = *(const volatile bf16x8*)(Abase + f * 64);          // hi
        af[f + 8] = *(const volatile bf16x8*)(Abase + 512 + f * 64);    // lo
    }

    float bv1[4], bv2[4]; int bi1[4], bi2[4];
    #pragma unroll
    for (int t = 0; t < 4; ++t) {
        bv1[t] = -3.0e38f; bv2[t] = -3.0e38f;
        bi1[t] = 0x7FFFFFFF; bi2[t] = 0x7FFFFFFF;
    }

    // stage chunk ch into lds[buf]; each wave copies its 4KB quarter
    auto stage = [&](int ch, int buf) {
        const char* s = Bchunk + (size_t)ch * 16384 + (size_t)w * 4096
                        + (size_t)l * 16;
        char* d = &lds[buf][w * 4096];
        gload_lds16(s,        d);
        gload_lds16(s + 1024, d + 1024);
        gload_lds16(s + 2048, d + 2048);
        gload_lds16(s + 3072, d + 3072);
    };

    stage(0, 0);
    __syncthreads();   // chunk 0 resident

    for (int c = 0; c < 128; ++c) {
        const int buf = c & 1;
        if (c + 1 < 128) stage(c + 1, buf ^ 1);   // latency hides under compute

        const char* p = &lds[buf][l * 16];
        f32x4 a0 = {0.f,0.f,0.f,0.f}, a1 = a0, a2 = a0, a3 = a0;
        // 3-term split, 2 B-frags live at a time (8 regs):
        // hi*hi (af[f] x bh), lo*hi (af[f+8] x bh), hi*lo (af[f] x bl)
        #pragma unroll
        for (int f = 0; f < 8; f += 2) {
            bf16x8 bh0 = *(const bf16x8*)(p + (size_t)f * 1024);
            bf16x8 bl0 = *(const bf16x8*)(p + (size_t)(f + 8) * 1024);
            a0 = __builtin_amdgcn_mfma_f32_16x16x32_bf16(af[f],   bh0, a0, 0,0,0);
            a1 = __builtin_amdgcn_mfma_f32_16x16x32_bf16(af[f+8], bh0, a1, 0,0,0);
            a2 = __builtin_amdgcn_mfma_f32_16x16x32_bf16(af[f],   bl0, a2, 0,0,0);
            bf16x8 bh1 = *(const bf16x8*)(p + (size_t)(f + 1) * 1024);
            bf16x8 bl1 = *(const bf16x8*)(p + (size_t)(f + 9) * 1024);
            a3 = __builtin_amdgcn_mfma_f32_16x16x32_bf16(af[f+1], bh1, a3, 0,0,0);
            a0 = __builtin_amdgcn_mfma_f32_16x16x32_bf16(af[f+9], bh1, a0, 0,0,0);
            a1 = __builtin_amdgcn_mfma_f32_16x16x32_bf16(af[f+1], bl1, a1, 0,0,0);
        }
        f32x4 s01 = a0 + a1, s23 = a2 + a3;
        f32x4 s = s01 + s23;

        const int colbase = n0 + c * 16 + (l & 15);
        #pragma unroll
        for (int t = 0; t < 4; ++t)
            push2(bv1[t], bi1[t], bv2[t], bi2[t], s[t], colbase);

        __syncthreads();  // chunk c+1 landed; reads of buf done before overwrite
    }

    // merge across the 16 col-lanes (xor masks 1,2,4,8); C/D layout:
    // col = lane&15, row = (lane>>4)*4 + reg
    #pragma unroll
    for (int t = 0; t < 4; ++t) {
        float v1 = bv1[t], v2 = bv2[t];
        int   i1 = bi1[t], i2 = bi2[t];
        #pragma unroll
        for (int mask = 1; mask < 16; mask <<= 1) {
            float ov1 = __shfl_xor(v1, mask, 64);
            int   oi1 = __shfl_xor(i1, mask, 64);
            float ov2 = __shfl_xor(v2, mask, 64);
            int   oi2 = __shfl_xor(i2, mask, 64);
            push2(v1, i1, v2, i2, ov1, oi1);
            push2(v1, i1, v2, i2, ov2, oi2);
        }
        if ((l & 15) == 0) {
            const int row = m0 + (l >> 4) * 4 + t;
            float4 o;
            o.x = v1; o.y = __int_as_float(i1);
            o.z = v2; o.w = __int_as_float(i2);
            *(float4*)&Part[((size_t)row * 4 + ks) * 4] = o;
        }
    }
}

// ---------------------------------------------------------------------------
// argmax reduce + exact fp32 recheck: merge 4 ks-partials/row -> top2,
// recompute both candidate dots in fp32, pick winner (tie -> smaller index).
// grid 4096 x 256 (wave per row).
// ---------------------------------------------------------------------------
__global__ __launch_bounds__(256) void argmax_kernel(
    const float* __restrict__ Part, const float* __restrict__ Zt,
    const float* __restrict__ cb, const float* __restrict__ invn,
    int* __restrict__ idxout, float* __restrict__ fidxout)
{
    const int w = threadIdx.x >> 6, l = threadIdx.x & 63;
    const int row = blockIdx.x * 4 + w;
    float v1 = -3.0e38f, v2 = -3.0e38f;
    int   i1 = 0x7FFFFFFF, i2 = 0x7FFFFFFF;
    if (l < 4) {
        float4 p = *(const float4*)&Part[((size_t)row * 4 + l) * 4];
        v1 = p.x; i1 = __float_as_int(p.y);
        v2 = p.z; i2 = __float_as_int(p.w);
    }
    #pragma unroll
    for (int mask = 1; mask < 4; mask <<= 1) {
        float ov1 = __shfl_xor(v1, mask, 64);
        int   oi1 = __shfl_xor(i1, mask, 64);
        float ov2 = __shfl_xor(v2, mask, 64);
        int   oi2 = __shfl_xor(i2, mask, 64);
        push2(v1, i1, v2, i2, ov1, oi1);
        push2(v1, i1, v2, i2, ov2, oi2);
    }
    // broadcast lane 0's top2 to all lanes
    v1 = __shfl(v1, 0, 64); i1 = __shfl(i1, 0, 64);
    v2 = __shfl(v2, 0, 64); i2 = __shfl(i2, 0, 64);
    // exact fp32 dots for the two candidates
    const float* z  = Zt + (size_t)row * D_;
    float4 zv = *(const float4*)(z + l*4);
    float4 a  = *(const float4*)(cb + (size_t)i1 * D_ + l*4);
    float4 b  = *(const float4*)(cb + (size_t)i2 * D_ + l*4);
    float s1 = zv.x*a.x + zv.y*a.y + zv.z*a.z + zv.w*a.w;
    float s2 = zv.x*b.x + zv.y*b.y + zv.z*b.z + zv.w*b.w;
    s1 = waveReduceSum64(s1);
    s2 = waveReduceSum64(s2);
    float e1 = s1 * invn[i1];
    float e2 = s2 * invn[i2];
    int win = (e2 > e1 || (e2 == e1 && i2 < i1)) ? i2 : i1;
    if (l == 0) { idxout[row] = win; fidxout[row] = (float)win; }
}

// ---------------------------------------------------------------------------
// losses: S[n] = sum_{l,d} (cb[idx[n,l]][d] - Zt[n*L+l][d])^2
// ---------------------------------------------------------------------------
__global__ __launch_bounds__(256) void loss_kernel(
    const float* __restrict__ Zt, const float* __restrict__ cb,
    const int* __restrict__ idx, float* __restrict__ lossacc)
{
    __shared__ float red[4];
    const int tid = threadIdx.x;
    const int r = blockIdx.x * 64 + (tid >> 2);
    const int q = tid & 3;
    const int n = r >> 12;
    const int code = idx[r];
    const float* zp = Zt + (size_t)r * D_ + q * 64;
    const float* cp = cb + (size_t)code * D_ + q * 64;
    float s = 0.0f;
    #pragma unroll
    for (int it = 0; it < 16; ++it) {
        float4 a = *(const float4*)(zp + it*4);
        float4 c = *(const float4*)(cp + it*4);
        float dx = c.x - a.x, dy = c.y - a.y, dz = c.z - a.z, dw = c.w - a.w;
        s += dx*dx + dy*dy + dz*dz + dw*dw;
    }
    s = waveReduceSum64(s);
    if ((tid & 63) == 0) red[tid >> 6] = s;
    __syncthreads();
    if (tid == 0) atomicAdd(&lossacc[n], red[0] + red[1] + red[2] + red[3]);
}

// ---------------------------------------------------------------------------
// y gather: y[n][c][l] = P[idx[n,l]][c] + out_b[c]
// ---------------------------------------------------------------------------
__global__ __launch_bounds__(256) void y_kernel(
    const float* __restrict__ P, const int* __restrict__ idx,
    const float* __restrict__ outb, float* __restrict__ y)
{
    __shared__ float bias[128];
    const int t = threadIdx.x;
    const int c0 = blockIdx.y * 128;
    const int n = blockIdx.z;
    const int l = blockIdx.x * 256 + t;
    if (t < 128) bias[t] = outb[c0 + t];
    __syncthreads();
    const int code = idx[n * L_ + l];
    const float* prow = P + (size_t)code * C_ + c0;
    float* yb = y + ((size_t)n * C_ + c0) * L_ + l;
    #pragma unroll 4
    for (int c = 0; c < 128; ++c) {
        yb[(size_t)c * L_] = prow[c] + bias[c];
    }
}

__global__ __launch_bounds__(64) void fin_kernel(
    const float* __restrict__ lossacc, float* __restrict__ out)
{
    const int t = threadIdx.x;
    if (t < 8) out[t] = lossacc[t & 3] * (1.0f / (float)(D_ * L_));
}

extern "C" void kernel_launch(void* const* d_in, const int* in_sizes, int n_in,
                              void* d_out, int out_size, void* d_ws, size_t ws_size,
                              hipStream_t stream) {
    (void)in_sizes; (void)n_in; (void)out_size; (void)ws_size;
    const float* x     = (const float*)d_in[0];
    const float* in_v  = (const float*)d_in[1];
    const float* in_g  = (const float*)d_in[2];
    const float* in_b  = (const float*)d_in[3];
    const float* out_v = (const float*)d_in[4];
    const float* out_g = (const float*)d_in[5];
    const float* out_b = (const float*)d_in[6];
    const float* cb    = (const float*)d_in[7];
    float* out = (float*)d_out;
    float* ws  = (float*)d_ws;

    float*          Zt     = ws + WS_ZT;
    float*          P      = ws + WS_P;
    unsigned short* Z2     = (unsigned short*)(ws + WS_Z2);
    unsigned short* CB2F   = (unsigned short*)(ws + WS_CB2);
    float*          Part   = ws + WS_PART;
    float*          Win    = ws + WS_WIN;
    float*          Wout   = ws + WS_WOUT;
    float*          invn   = ws + WS_INVN;
    int*            idx    = (int*)(ws + WS_IDX);
    float*          lossac = ws + WS_LOSS;

    prep_kernel<<<dim3(D_ + C_), 64, 0, stream>>>(in_v, in_g, out_v, out_g,
                                                  Win, Wout, lossac);
    cb2_kernel<<<dim3(K_), 64, 0, stream>>>(cb, invn);
    cb2f_kernel<<<dim3(512), 256, 0, stream>>>(cb, invn, CB2F);
    ze_kernel<<<dim3(64, 4, 4), 256, 0, stream>>>(x, Win, in_b, Zt, Z2);
    pmat_kernel<<<dim3(128, 8), 256, 0, stream>>>(cb, Wout, P);
    sim_kernel<<<dim3(1024), 256, 0, stream>>>(Z2, CB2F, Part);
    argmax_kernel<<<dim3(4096), 256, 0, stream>>>(Part, Zt, cb, invn,
                                                  idx, out + OUT_IDX_OFF);
    loss_kernel<<<dim3(256), 256, 0, stream>>>(Zt, cb, idx, lossac);
    y_kernel<<<dim3(16, 4, 4), 256, 0, stream>>>(P, idx, out_b, out);
    fin_kernel<<<dim3(1), 64, 0, stream>>>(lossac, out + OUT_CB_OFF);
}

// Round 7
// 618.769 us; speedup vs baseline: 1.2210x; 1.0049x over previous
//
#include <hip/hip_runtime.h>
#include <math.h>

// Problem dims
#define N_ 4
#define C_ 512
#define L_ 4096
#define D_ 256
#define K_ 8192
#define NL_ 16384           // N_*L_

// d_out layout (float32 flat): y | code_index(as float) | cb_loss | cm_loss
#define OUT_IDX_OFF (N_*C_*L_)          // 8388608
#define OUT_CB_OFF  (OUT_IDX_OFF + NL_) // 8404992

// ws layout (float units).
#define WS_ZT   0                                  // Zt[16384][256] f32
#define WS_P    (WS_ZT + (size_t)NL_*D_)           // P[8192][512] f32
#define WS_Z2   (WS_P + (size_t)K_*C_)             // Z2[16384][512] bf16 (hi|lo row-major)
#define WS_CB2  (WS_Z2 + (size_t)NL_*D_)           // CB2F[512 c16][16 frag][64 lane][8] bf16
#define WS_PART (WS_CB2 + (size_t)K_*D_)           // Part[16384][4 ks][4] f32 top2 partials
#define WS_WIN  (WS_PART + (size_t)NL_*64*4)       // W_in[256][512]
#define WS_WOUT (WS_WIN + (size_t)D_*C_)           // W_out[512][256]
#define WS_INVN (WS_WOUT + (size_t)C_*D_)          // inv codebook norms [8192]
#define WS_IDX  (WS_INVN + (size_t)K_)             // idx[16384] (int)
#define WS_LOSS (WS_IDX + (size_t)NL_)             // loss accum [4]

typedef __bf16 bf16x8 __attribute__((ext_vector_type(8)));
typedef float  f32x4  __attribute__((ext_vector_type(4)));
typedef unsigned int u32;

__device__ __forceinline__ unsigned short f2bf(float f) {   // round-nearest-even
    u32 u = __float_as_uint(f);
    u32 r = (u + 0x7fffu + ((u >> 16) & 1u)) >> 16;
    return (unsigned short)r;
}
__device__ __forceinline__ float bf2f(unsigned short h) {
    return __uint_as_float(((u32)h) << 16);
}

__device__ __forceinline__ float waveReduceSum64(float s) {
    #pragma unroll
    for (int off = 32; off; off >>= 1) s += __shfl_xor(s, off, 64);
    return s;
}

// prefer (av,ai) over (bv,bi)?  larger value wins; tie -> smaller index
__device__ __forceinline__ bool pref(float av, int ai, float bv, int bi) {
    return (av > bv) || (av == bv && ai < bi);
}
// push candidate (wv,wi) into sorted top2 (v1,i1,v2,i2)
__device__ __forceinline__ void push2(float& v1, int& i1, float& v2, int& i2,
                                      float wv, int wi) {
    if (pref(wv, wi, v1, i1)) { v2 = v1; i2 = i1; v1 = wv; i1 = wi; }
    else if (pref(wv, wi, v2, i2)) { v2 = wv; i2 = wi; }
}

// async global->LDS copy, 16B per lane; lds dest must be wave-uniform base
__device__ __forceinline__ void gload_lds16(const void* g, void* l) {
    __builtin_amdgcn_global_load_lds(
        (const __attribute__((address_space(1))) void*)g,
        (__attribute__((address_space(3))) void*)l,
        16, 0, 0);
}

// ---------------------------------------------------------------------------
// prep: W_in = g*v/||v||, W_out likewise, zero loss accum.
// ---------------------------------------------------------------------------
__global__ __launch_bounds__(64) void prep_kernel(
    const float* __restrict__ in_v, const float* __restrict__ in_g,
    const float* __restrict__ out_v, const float* __restrict__ out_g,
    float* __restrict__ Win, float* __restrict__ Wout,
    float* __restrict__ lossacc)
{
    const int b = blockIdx.x;
    const int t = threadIdx.x;
    if (b == 0 && t < N_) lossacc[t] = 0.0f;
    if (b < D_) {
        const float* v = in_v + (size_t)b * C_;
        float4 a0 = *(const float4*)(v + t * 4);
        float4 a1 = *(const float4*)(v + 256 + t * 4);
        float s = a0.x*a0.x + a0.y*a0.y + a0.z*a0.z + a0.w*a0.w
                + a1.x*a1.x + a1.y*a1.y + a1.z*a1.z + a1.w*a1.w;
        s = waveReduceSum64(s);
        float scale = in_g[b] / sqrtf(s);
        float* w = Win + (size_t)b * C_;
        float4 o0, o1;
        o0.x=a0.x*scale; o0.y=a0.y*scale; o0.z=a0.z*scale; o0.w=a0.w*scale;
        o1.x=a1.x*scale; o1.y=a1.y*scale; o1.z=a1.z*scale; o1.w=a1.w*scale;
        *(float4*)(w + t*4) = o0;
        *(float4*)(w + 256 + t*4) = o1;
    } else {
        const int r = b - D_;
        const float* v = out_v + (size_t)r * D_;
        float4 a0 = *(const float4*)(v + t * 4);
        float s = a0.x*a0.x + a0.y*a0.y + a0.z*a0.z + a0.w*a0.w;
        s = waveReduceSum64(s);
        float scale = out_g[r] / sqrtf(s);
        float4 o0;
        o0.x=a0.x*scale; o0.y=a0.y*scale; o0.z=a0.z*scale; o0.w=a0.w*scale;
        *(float4*)(Wout + (size_t)r * D_ + t*4) = o0;
    }
}

// ---------------------------------------------------------------------------
// cb2: invn[k] = 1/max(||cb_k||,eps).  grid 8192 x 64
// ---------------------------------------------------------------------------
__global__ __launch_bounds__(64) void cb2_kernel(
    const float* __restrict__ cb, float* __restrict__ invn)
{
    const int k = blockIdx.x;
    const int t = threadIdx.x;
    float4 v = *(const float4*)(cb + (size_t)k * D_ + t * 4);
    float s = v.x*v.x + v.y*v.y + v.z*v.z + v.w*v.w;
    s = waveReduceSum64(s);
    if (t == 0) invn[k] = 1.0f / fmaxf(sqrtf(s), 1e-8f);
}

// ---------------------------------------------------------------------------
// cb2f: build B-fragment-ordered split codebook.
// Layout: frag(c16, kc) = 1 KB at ((c16*16 + kc)*64 lanes)*8 shorts.
// MFMA B-operand lane map (16x16x32): lane = (klocal>>3)*16 + n, j = klocal&7.
// kc 0..7: hi(d = kc*32 + klocal), scaled by invn; kc 8..15: lo of same d.
// grid 512 x 256.  thread t: kc = t>>4, n = t&15, covers d-range (kc&7)*32..+31.
// ---------------------------------------------------------------------------
__global__ __launch_bounds__(256) void cb2f_kernel(
    const float* __restrict__ cb, const float* __restrict__ invn,
    unsigned short* __restrict__ CB2F)
{
    const int c16 = blockIdx.x;
    const int t = threadIdx.x;
    const int kc = t >> 4, nl = t & 15;
    const int code = c16 * 16 + nl;
    const float inv = invn[code];
    const float* src = cb + (size_t)code * D_ + (kc & 7) * 32;
    unsigned short* dst = CB2F + ((size_t)(c16 * 16 + kc) * 64) * 8;
    #pragma unroll
    for (int lh = 0; lh < 4; ++lh) {
        float4 x0 = *(const float4*)(src + lh * 8);
        float4 x1 = *(const float4*)(src + lh * 8 + 4);
        float f[8] = {x0.x, x0.y, x0.z, x0.w, x1.x, x1.y, x1.z, x1.w};
        unsigned short o[8];
        #pragma unroll
        for (int j = 0; j < 8; ++j) {
            float v = f[j] * inv;
            unsigned short h = f2bf(v);
            o[j] = (kc < 8) ? h : f2bf(v - bf2f(h));
        }
        unsigned short* dp = dst + (lh * 16 + nl) * 8;
        *(ushort4*)&dp[0] = make_ushort4(o[0], o[1], o[2], o[3]);
        *(ushort4*)&dp[4] = make_ushort4(o[4], o[5], o[6], o[7]);
    }
}

// ---------------------------------------------------------------------------
// z_e GEMM: Zt[n*L+l][d] = sum_c x[n][c][l]*Win[d][c] + in_b[d]; also writes
// bf16 split Z2[row] = [hi | lo] row-major.
// ---------------------------------------------------------------------------
__global__ __launch_bounds__(256) void ze_kernel(
    const float* __restrict__ x, const float* __restrict__ Win,
    const float* __restrict__ inb, float* __restrict__ Zt,
    unsigned short* __restrict__ Z2)
{
    __shared__ float Al[2][16][64];   // x tile [c][l]
    __shared__ float Bl[2][16][68];   // Win tile [c][d] (padded)
    const int tid = threadIdx.x;
    const int ty = tid >> 4, tx = tid & 15;
    const int l0 = blockIdx.x * 64;
    const int d0 = blockIdx.y * 64;
    const int n  = blockIdx.z;
    const float* xn = x + (size_t)n * C_ * L_;

    const int ac = tid >> 4, alq = tid & 15;
    const int bd = tid >> 2, bq  = tid & 3;

    float acc[4][4];
    #pragma unroll
    for (int i = 0; i < 4; ++i)
        #pragma unroll
        for (int j = 0; j < 4; ++j) acc[i][j] = 0.0f;

    auto stage = [&](int cc, int buf) {
        float4 av = *(const float4*)(xn + (size_t)(cc*16 + ac) * L_ + l0 + alq*4);
        *(float4*)&Al[buf][ac][alq*4] = av;
        float4 bv = *(const float4*)(Win + (size_t)(d0 + bd) * C_ + cc*16 + bq*4);
        Bl[buf][bq*4+0][bd] = bv.x; Bl[buf][bq*4+1][bd] = bv.y;
        Bl[buf][bq*4+2][bd] = bv.z; Bl[buf][bq*4+3][bd] = bv.w;
    };

    stage(0, 0);
    for (int cc = 0; cc < 32; ++cc) {
        __syncthreads();
        if (cc + 1 < 32) stage(cc + 1, (cc + 1) & 1);
        const int buf = cc & 1;
        #pragma unroll
        for (int k = 0; k < 16; ++k) {
            float4 a = *(const float4*)&Al[buf][k][ty*4];
            float4 b = *(const float4*)&Bl[buf][k][tx*4];
            acc[0][0]=fmaf(a.x,b.x,acc[0][0]); acc[0][1]=fmaf(a.x,b.y,acc[0][1]);
            acc[0][2]=fmaf(a.x,b.z,acc[0][2]); acc[0][3]=fmaf(a.x,b.w,acc[0][3]);
            acc[1][0]=fmaf(a.y,b.x,acc[1][0]); acc[1][1]=fmaf(a.y,b.y,acc[1][1]);
            acc[1][2]=fmaf(a.y,b.z,acc[1][2]); acc[1][3]=fmaf(a.y,b.w,acc[1][3]);
            acc[2][0]=fmaf(a.z,b.x,acc[2][0]); acc[2][1]=fmaf(a.z,b.y,acc[2][1]);
            acc[2][2]=fmaf(a.z,b.z,acc[2][2]); acc[2][3]=fmaf(a.z,b.w,acc[2][3]);
            acc[3][0]=fmaf(a.w,b.x,acc[3][0]); acc[3][1]=fmaf(a.w,b.y,acc[3][1]);
            acc[3][2]=fmaf(a.w,b.z,acc[3][2]); acc[3][3]=fmaf(a.w,b.w,acc[3][3]);
        }
    }
    float4 bias = *(const float4*)(inb + d0 + tx*4);
    #pragma unroll
    for (int i = 0; i < 4; ++i) {
        float4 o;
        o.x = acc[i][0] + bias.x; o.y = acc[i][1] + bias.y;
        o.z = acc[i][2] + bias.z; o.w = acc[i][3] + bias.w;
        const size_t row = (size_t)(n*L_ + l0 + ty*4 + i);
        *(float4*)&Zt[row * D_ + d0 + tx*4] = o;
        ushort4 h, lo;
        h.x = f2bf(o.x); h.y = f2bf(o.y); h.z = f2bf(o.z); h.w = f2bf(o.w);
        lo.x = f2bf(o.x - bf2f(h.x)); lo.y = f2bf(o.y - bf2f(h.y));
        lo.z = f2bf(o.z - bf2f(h.z)); lo.w = f2bf(o.w - bf2f(h.w));
        *(ushort4*)&Z2[row * 512 + d0 + tx*4]       = h;
        *(ushort4*)&Z2[row * 512 + 256 + d0 + tx*4] = lo;
    }
}

// ---------------------------------------------------------------------------
// P GEMM: P[k][c] = sum_d cb[k][d] * Wout[c][d]    (8192 x 512 x 256)
// ---------------------------------------------------------------------------
__global__ __launch_bounds__(256) void pmat_kernel(
    const float* __restrict__ cb, const float* __restrict__ Wout,
    float* __restrict__ P)
{
    __shared__ float Al[2][16][68];
    __shared__ float Bl[2][16][68];
    const int tid = threadIdx.x;
    const int ty = tid >> 4, tx = tid & 15;
    const int k0 = blockIdx.x * 64;
    const int c0 = blockIdx.y * 64;
    const int ar = tid >> 2, aq = tid & 3;

    float acc[4][4];
    #pragma unroll
    for (int i = 0; i < 4; ++i)
        #pragma unroll
        for (int j = 0; j < 4; ++j) acc[i][j] = 0.0f;

    auto stage = [&](int dc, int buf) {
        float4 av = *(const float4*)(cb + (size_t)(k0 + ar) * D_ + dc*16 + aq*4);
        Al[buf][aq*4+0][ar] = av.x; Al[buf][aq*4+1][ar] = av.y;
        Al[buf][aq*4+2][ar] = av.z; Al[buf][aq*4+3][ar] = av.w;
        float4 bv = *(const float4*)(Wout + (size_t)(c0 + ar) * D_ + dc*16 + aq*4);
        Bl[buf][aq*4+0][ar] = bv.x; Bl[buf][aq*4+1][ar] = bv.y;
        Bl[buf][aq*4+2][ar] = bv.z; Bl[buf][aq*4+3][ar] = bv.w;
    };

    stage(0, 0);
    for (int dc = 0; dc < 16; ++dc) {
        __syncthreads();
        if (dc + 1 < 16) stage(dc + 1, (dc + 1) & 1);
        const int buf = dc & 1;
        #pragma unroll
        for (int k = 0; k < 16; ++k) {
            float4 a = *(const float4*)&Al[buf][k][ty*4];
            float4 b = *(const float4*)&Bl[buf][k][tx*4];
            acc[0][0]=fmaf(a.x,b.x,acc[0][0]); acc[0][1]=fmaf(a.x,b.y,acc[0][1]);
            acc[0][2]=fmaf(a.x,b.z,acc[0][2]); acc[0][3]=fmaf(a.x,b.w,acc[0][3]);
            acc[1][0]=fmaf(a.y,b.x,acc[1][0]); acc[1][1]=fmaf(a.y,b.y,acc[1][1]);
            acc[1][2]=fmaf(a.y,b.z,acc[1][2]); acc[1][3]=fmaf(a.y,b.w,acc[1][3]);
            acc[2][0]=fmaf(a.z,b.x,acc[2][0]); acc[2][1]=fmaf(a.z,b.y,acc[2][1]);
            acc[2][2]=fmaf(a.z,b.z,acc[2][2]); acc[2][3]=fmaf(a.z,b.w,acc[2][3]);
            acc[3][0]=fmaf(a.w,b.x,acc[3][0]); acc[3][1]=fmaf(a.w,b.y,acc[3][1]);
            acc[3][2]=fmaf(a.w,b.z,acc[3][2]); acc[3][3]=fmaf(a.w,b.w,acc[3][3]);
        }
    }
    #pragma unroll
    for (int i = 0; i < 4; ++i) {
        float4 o;
        o.x = acc[i][0]; o.y = acc[i][1]; o.z = acc[i][2]; o.w = acc[i][3];
        *(float4*)&P[(size_t)(k0 + ty*4 + i) * C_ + c0 + tx*4] = o;
    }
}

// ---------------------------------------------------------------------------
// sim (MFMA): v8 -- v7 minus the spill: 3 acc chains, 2 live B-frags.
// v7 post-mortem: occupancy fix worked (22.8->41.4%, 515->422us) but
// WRITE_SIZE stayed at 630MB -> still spilling ~6-8 regs/iter under the
// 128-reg cap (demand was af 64 + acc 16 + bg-live 16 + top2 16 + misc ~20
// = ~132-136).  Spill writes = 1.5TB/s of the observed HBM traffic plus
// scratch re-read latency on the critical path.
// v8 trims 12 regs with identical arithmetic: per step load bh=frag[f],
// bl=frag[f+8] (8 regs live) and run 3 chains a0+=af[f]*bh (hi*hi),
// a1+=af[f+8]*bh (lo*hi), a2+=af[f]*bl (hi*lo).  Demand ~116 <= 128.
// Everything else identical to v7 (2x16KB dbuf, __syncthreads, grid 1024,
// 4 blocks/CU).  Verify: WRITE_SIZE ~65MB (THE signal), occupancy ~41%.
// ---------------------------------------------------------------------------
__global__ __launch_bounds__(256, 4) void sim_kernel(
    const unsigned short* __restrict__ Z2, const unsigned short* __restrict__ CB2F,
    float* __restrict__ Part)
{
    __shared__ char lds[2][16384];
    const int tid = threadIdx.x;
    const int w = tid >> 6, l = tid & 63;
    const int bid = blockIdx.x;
    const int ks = bid & 3;             // code range (constant per XCD)
    const int mtile = bid >> 2;         // 0..255
    const int m0 = mtile * 64 + w * 16;
    const int n0 = ks * 2048;
    const char* Bchunk = (const char*)CB2F + (size_t)(n0 >> 4) * 16384;

    // A fragments: lane holds A[m][k], m = l&15, klocal = (l>>4)*8 + j.
    // volatile: load exactly once (no sink/remat); 64 regs, AGPR-eligible.
    const char* Abase = (const char*)Z2 + (size_t)(m0 + (l & 15)) * 1024
                        + ((l >> 4) * 16);
    bf16x8 af[16];
    #pragma unroll
    for (int f = 0; f < 8; ++f) {
        af[f]     = *(const volatile bf16x8*)(Abase + f * 64);          // hi
        af[f + 8] = *(const volatile bf16x8*)(Abase + 512 + f * 64);    // lo
    }

    float bv1[4], bv2[4]; int bi1[4], bi2[4];
    #pragma unroll
    for (int t = 0; t < 4; ++t) {
        bv1[t] = -3.0e38f; bv2[t] = -3.0e38f;
        bi1[t] = 0x7FFFFFFF; bi2[t] = 0x7FFFFFFF;
    }

    // stage chunk ch into lds[buf]; each wave copies its 4KB quarter
    auto stage = [&](int ch, int buf) {
        const char* s = Bchunk + (size_t)ch * 16384 + (size_t)w * 4096
                        + (size_t)l * 16;
        char* d = &lds[buf][w * 4096];
        gload_lds16(s,        d);
        gload_lds16(s + 1024, d + 1024);
        gload_lds16(s + 2048, d + 2048);
        gload_lds16(s + 3072, d + 3072);
    };

    stage(0, 0);
    __syncthreads();   // chunk 0 resident

    for (int c = 0; c < 128; ++c) {
        const int buf = c & 1;
        if (c + 1 < 128) stage(c + 1, buf ^ 1);   // latency hides under compute

        const char* p = &lds[buf][l * 16];
        f32x4 a0 = {0.f,0.f,0.f,0.f}, a1 = a0, a2 = a0;
        // 3-term split, 3 chains, 2 B-frags live (8 regs):
        // hi*hi (af[f] x bh), lo*hi (af[f+8] x bh), hi*lo (af[f] x bl)
        #pragma unroll
        for (int f = 0; f < 8; ++f) {
            bf16x8 bh = *(const bf16x8*)(p + (size_t)f * 1024);
            bf16x8 bl = *(const bf16x8*)(p + (size_t)(f + 8) * 1024);
            a0 = __builtin_amdgcn_mfma_f32_16x16x32_bf16(af[f],   bh, a0, 0,0,0);
            a1 = __builtin_amdgcn_mfma_f32_16x16x32_bf16(af[f+8], bh, a1, 0,0,0);
            a2 = __builtin_amdgcn_mfma_f32_16x16x32_bf16(af[f],   bl, a2, 0,0,0);
        }
        f32x4 s01 = a0 + a1;
        f32x4 s = s01 + a2;

        const int colbase = n0 + c * 16 + (l & 15);
        #pragma unroll
        for (int t = 0; t < 4; ++t)
            push2(bv1[t], bi1[t], bv2[t], bi2[t], s[t], colbase);

        __syncthreads();  // chunk c+1 landed; reads of buf done before overwrite
    }

    // merge across the 16 col-lanes (xor masks 1,2,4,8); C/D layout:
    // col = lane&15, row = (lane>>4)*4 + reg
    #pragma unroll
    for (int t = 0; t < 4; ++t) {
        float v1 = bv1[t], v2 = bv2[t];
        int   i1 = bi1[t], i2 = bi2[t];
        #pragma unroll
        for (int mask = 1; mask < 16; mask <<= 1) {
            float ov1 = __shfl_xor(v1, mask, 64);
            int   oi1 = __shfl_xor(i1, mask, 64);
            float ov2 = __shfl_xor(v2, mask, 64);
            int   oi2 = __shfl_xor(i2, mask, 64);
            push2(v1, i1, v2, i2, ov1, oi1);
            push2(v1, i1, v2, i2, ov2, oi2);
        }
        if ((l & 15) == 0) {
            const int row = m0 + (l >> 4) * 4 + t;
            float4 o;
            o.x = v1; o.y = __int_as_float(i1);
            o.z = v2; o.w = __int_as_float(i2);
            *(float4*)&Part[((size_t)row * 4 + ks) * 4] = o;
        }
    }
}

// ---------------------------------------------------------------------------
// argmax reduce + exact fp32 recheck: merge 4 ks-partials/row -> top2,
// recompute both candidate dots in fp32, pick winner (tie -> smaller index).
// grid 4096 x 256 (wave per row).
// ---------------------------------------------------------------------------
__global__ __launch_bounds__(256) void argmax_kernel(
    const float* __restrict__ Part, const float* __restrict__ Zt,
    const float* __restrict__ cb, const float* __restrict__ invn,
    int* __restrict__ idxout, float* __restrict__ fidxout)
{
    const int w = threadIdx.x >> 6, l = threadIdx.x & 63;
    const int row = blockIdx.x * 4 + w;
    float v1 = -3.0e38f, v2 = -3.0e38f;
    int   i1 = 0x7FFFFFFF, i2 = 0x7FFFFFFF;
    if (l < 4) {
        float4 p = *(const float4*)&Part[((size_t)row * 4 + l) * 4];
        v1 = p.x; i1 = __float_as_int(p.y);
        v2 = p.z; i2 = __float_as_int(p.w);
    }
    #pragma unroll
    for (int mask = 1; mask < 4; mask <<= 1) {
        float ov1 = __shfl_xor(v1, mask, 64);
        int   oi1 = __shfl_xor(i1, mask, 64);
        float ov2 = __shfl_xor(v2, mask, 64);
        int   oi2 = __shfl_xor(i2, mask, 64);
        push2(v1, i1, v2, i2, ov1, oi1);
        push2(v1, i1, v2, i2, ov2, oi2);
    }
    // broadcast lane 0's top2 to all lanes
    v1 = __shfl(v1, 0, 64); i1 = __shfl(i1, 0, 64);
    v2 = __shfl(v2, 0, 64); i2 = __shfl(i2, 0, 64);
    // exact fp32 dots for the two candidates
    const float* z  = Zt + (size_t)row * D_;
    float4 zv = *(const float4*)(z + l*4);
    float4 a  = *(const float4*)(cb + (size_t)i1 * D_ + l*4);
    float4 b  = *(const float4*)(cb + (size_t)i2 * D_ + l*4);
    float s1 = zv.x*a.x + zv.y*a.y + zv.z*a.z + zv.w*a.w;
    float s2 = zv.x*b.x + zv.y*b.y + zv.z*b.z + zv.w*b.w;
    s1 = waveReduceSum64(s1);
    s2 = waveReduceSum64(s2);
    float e1 = s1 * invn[i1];
    float e2 = s2 * invn[i2];
    int win = (e2 > e1 || (e2 == e1 && i2 < i1)) ? i2 : i1;
    if (l == 0) { idxout[row] = win; fidxout[row] = (float)win; }
}

// ---------------------------------------------------------------------------
// losses: S[n] = sum_{l,d} (cb[idx[n,l]][d] - Zt[n*L+l][d])^2
// ---------------------------------------------------------------------------
__global__ __launch_bounds__(256) void loss_kernel(
    const float* __restrict__ Zt, const float* __restrict__ cb,
    const int* __restrict__ idx, float* __restrict__ lossacc)
{
    __shared__ float red[4];
    const int tid = threadIdx.x;
    const int r = blockIdx.x * 64 + (tid >> 2);
    const int q = tid & 3;
    const int n = r >> 12;
    const int code = idx[r];
    const float* zp = Zt + (size_t)r * D_ + q * 64;
    const float* cp = cb + (size_t)code * D_ + q * 64;
    float s = 0.0f;
    #pragma unroll
    for (int it = 0; it < 16; ++it) {
        float4 a = *(const float4*)(zp + it*4);
        float4 c = *(const float4*)(cp + it*4);
        float dx = c.x - a.x, dy = c.y - a.y, dz = c.z - a.z, dw = c.w - a.w;
        s += dx*dx + dy*dy + dz*dz + dw*dw;
    }
    s = waveReduceSum64(s);
    if ((tid & 63) == 0) red[tid >> 6] = s;
    __syncthreads();
    if (tid == 0) atomicAdd(&lossacc[n], red[0] + red[1] + red[2] + red[3]);
}

// ---------------------------------------------------------------------------
// y gather: y[n][c][l] = P[idx[n,l]][c] + out_b[c]
// ---------------------------------------------------------------------------
__global__ __launch_bounds__(256) void y_kernel(
    const float* __restrict__ P, const int* __restrict__ idx,
    const float* __restrict__ outb, float* __restrict__ y)
{
    __shared__ float bias[128];
    const int t = threadIdx.x;
    const int c0 = blockIdx.y * 128;
    const int n = blockIdx.z;
    const int l = blockIdx.x * 256 + t;
    if (t < 128) bias[t] = outb[c0 + t];
    __syncthreads();
    const int code = idx[n * L_ + l];
    const float* prow = P + (size_t)code * C_ + c0;
    float* yb = y + ((size_t)n * C_ + c0) * L_ + l;
    #pragma unroll 4
    for (int c = 0; c < 128; ++c) {
        yb[(size_t)c * L_] = prow[c] + bias[c];
    }
}

__global__ __launch_bounds__(64) void fin_kernel(
    const float* __restrict__ lossacc, float* __restrict__ out)
{
    const int t = threadIdx.x;
    if (t < 8) out[t] = lossacc[t & 3] * (1.0f / (float)(D_ * L_));
}

extern "C" void kernel_launch(void* const* d_in, const int* in_sizes, int n_in,
                              void* d_out, int out_size, void* d_ws, size_t ws_size,
                              hipStream_t stream) {
    (void)in_sizes; (void)n_in; (void)out_size; (void)ws_size;
    const float* x     = (const float*)d_in[0];
    const float* in_v  = (const float*)d_in[1];
    const float* in_g  = (const float*)d_in[2];
    const float* in_b  = (const float*)d_in[3];
    const float* out_v = (const float*)d_in[4];
    const float* out_g = (const float*)d_in[5];
    const float* out_b = (const float*)d_in[6];
    const float* cb    = (const float*)d_in[7];
    float* out = (float*)d_out;
    float* ws  = (float*)d_ws;

    float*          Zt     = ws + WS_ZT;
    float*          P      = ws + WS_P;
    unsigned short* Z2     = (unsigned short*)(ws + WS_Z2);
    unsigned short* CB2F   = (unsigned short*)(ws + WS_CB2);
    float*          Part   = ws + WS_PART;
    float*          Win    = ws + WS_WIN;
    float*          Wout   = ws + WS_WOUT;
    float*          invn   = ws + WS_INVN;
    int*            idx    = (int*)(ws + WS_IDX);
    float*          lossac = ws + WS_LOSS;

    prep_kernel<<<dim3(D_ + C_), 64, 0, stream>>>(in_v, in_g, out_v, out_g,
                                                  Win, Wout, lossac);
    cb2_kernel<<<dim3(K_), 64, 0, stream>>>(cb, invn);
    cb2f_kernel<<<dim3(512), 256, 0, stream>>>(cb, invn, CB2F);
    ze_kernel<<<dim3(64, 4, 4), 256, 0, stream>>>(x, Win, in_b, Zt, Z2);
    pmat_kernel<<<dim3(128, 8), 256, 0, stream>>>(cb, Wout, P);
    sim_kernel<<<dim3(1024), 256, 0, stream>>>(Z2, CB2F, Part);
    argmax_kernel<<<dim3(4096), 256, 0, stream>>>(Part, Zt, cb, invn,
                                                  idx, out + OUT_IDX_OFF);
    loss_kernel<<<dim3(256), 256, 0, stream>>>(Zt, cb, idx, lossac);
    y_kernel<<<dim3(16, 4, 4), 256, 0, stream>>>(P, idx, out_b, out);
    fin_kernel<<<dim3(1), 64, 0, stream>>>(lossac, out + OUT_CB_OFF);
}